// Round 1
// baseline (8815.546 us; speedup 1.0000x reference)
//
#include <hip/hip_runtime.h>
#include <hip/hip_bf16.h>

#define D_MODEL 512
#define NHEAD 8
#define HD 64
#define NSEQ 512
#define BATCH 16
#define LWIN 64

// ---------------------------------------------------------------------------
// embed: M[b,n,:] = M_emb[q + NQ*r] + P[n];  E[b,n,:] = E_emb[qry]
// grid = B*N blocks, 128 threads (float4 over 512)
// ---------------------------------------------------------------------------
__global__ __launch_bounds__(128) void embed_kernel(
    const int* __restrict__ q, const int* __restrict__ r, const int* __restrict__ qry,
    const float* __restrict__ M_emb, const float* __restrict__ E_emb,
    const float* __restrict__ P, float* __restrict__ M, float* __restrict__ E)
{
    const int t = blockIdx.x;              // b*N + n
    const int n = t & (NSEQ - 1);
    const int x = q[t] + 10000 * r[t];
    const int e = qry[t];
    const float4* me = (const float4*)(M_emb + (long)x * D_MODEL);
    const float4* pe = (const float4*)(P + (long)n * D_MODEL);
    const float4* ee = (const float4*)(E_emb + (long)e * D_MODEL);
    float4* Mo = (float4*)(M + (long)t * D_MODEL);
    float4* Eo = (float4*)(E + (long)t * D_MODEL);
    const int i = threadIdx.x;             // 0..127
    float4 a = me[i], p4 = pe[i];
    Mo[i] = make_float4(a.x + p4.x, a.y + p4.y, a.z + p4.z, a.w + p4.w);
    Eo[i] = ee[i];
}

// ---------------------------------------------------------------------------
// Generic GEMM: C[M x N] = A[M x K] @ W[N x K]^T + bias[N]  (optional relu)
// 64x64 tile, BK=16, 256 threads, 4x4 per-thread micro-tile.
// Requires M%64==0, N%64==0, K%16==0.
// grid = dim3(N/64, M/64)
// ---------------------------------------------------------------------------
__global__ __launch_bounds__(256) void gemm_xwT(
    const float* __restrict__ A, const float* __restrict__ W,
    const float* __restrict__ bias, float* __restrict__ C,
    int M, int N, int K, int relu)
{
    __shared__ float As[16][65];
    __shared__ float Ws[16][65];
    const int tid = threadIdx.x;
    const int n0 = blockIdx.x * 64;
    const int m0 = blockIdx.y * 64;
    const int tx = tid & 15;       // n micro
    const int ty = tid >> 4;       // m micro
    const int lrow = tid >> 2;     // 0..63
    const int lk4  = (tid & 3) * 4;

    float c[4][4] = {};

    for (int k0 = 0; k0 < K; k0 += 16) {
        float4 av = *(const float4*)(A + (long)(m0 + lrow) * K + k0 + lk4);
        float4 wv = *(const float4*)(W + (long)(n0 + lrow) * K + k0 + lk4);
        __syncthreads();   // protect previous iteration's LDS reads
        As[lk4 + 0][lrow] = av.x; As[lk4 + 1][lrow] = av.y;
        As[lk4 + 2][lrow] = av.z; As[lk4 + 3][lrow] = av.w;
        Ws[lk4 + 0][lrow] = wv.x; Ws[lk4 + 1][lrow] = wv.y;
        Ws[lk4 + 2][lrow] = wv.z; Ws[lk4 + 3][lrow] = wv.w;
        __syncthreads();
        #pragma unroll
        for (int kk = 0; kk < 16; ++kk) {
            float a0 = As[kk][ty * 4 + 0], a1 = As[kk][ty * 4 + 1];
            float a2 = As[kk][ty * 4 + 2], a3 = As[kk][ty * 4 + 3];
            float b0 = Ws[kk][tx * 4 + 0], b1 = Ws[kk][tx * 4 + 1];
            float b2 = Ws[kk][tx * 4 + 2], b3 = Ws[kk][tx * 4 + 3];
            c[0][0] += a0 * b0; c[0][1] += a0 * b1; c[0][2] += a0 * b2; c[0][3] += a0 * b3;
            c[1][0] += a1 * b0; c[1][1] += a1 * b1; c[1][2] += a1 * b2; c[1][3] += a1 * b3;
            c[2][0] += a2 * b0; c[2][1] += a2 * b1; c[2][2] += a2 * b2; c[2][3] += a2 * b3;
            c[3][0] += a3 * b0; c[3][1] += a3 * b1; c[3][2] += a3 * b2; c[3][3] += a3 * b3;
        }
    }

    float4 bv = *(const float4*)(bias + n0 + tx * 4);
    #pragma unroll
    for (int i = 0; i < 4; ++i) {
        float4 o;
        o.x = c[i][0] + bv.x; o.y = c[i][1] + bv.y;
        o.z = c[i][2] + bv.z; o.w = c[i][3] + bv.w;
        if (relu) {
            o.x = fmaxf(o.x, 0.f); o.y = fmaxf(o.y, 0.f);
            o.z = fmaxf(o.z, 0.f); o.w = fmaxf(o.w, 0.f);
        }
        *(float4*)(C + (long)(m0 + ty * 4 + i) * N + n0 + tx * 4) = o;
    }
}

// ---------------------------------------------------------------------------
// Attention: one workgroup per (b, q); loops over all 8 heads.
// Q,K,V are (B*Nq x 512) / (B*Nkv x 512) row-major, head h at cols h*64..
// Writes O (B*Nq x 512). If attn_out != nullptr also writes head-mean probs
// at attn_out[b*Nq*Nkv + q*Nkv + k].
// causal: mask keys k > q.  grid = B*Nq blocks, 256 threads.
// ---------------------------------------------------------------------------
__global__ __launch_bounds__(256) void attn_kernel(
    const float* __restrict__ Q, const float* __restrict__ Km,
    const float* __restrict__ Vm, float* __restrict__ O,
    float* __restrict__ attn_out, int Nq, int Nkv, int causal)
{
    const int tid = threadIdx.x;
    const int bq = blockIdx.x;       // b*Nq + qi
    const int b = bq / Nq;
    const int qi = bq - b * Nq;

    __shared__ float qs[64];
    __shared__ float sc[512];
    __shared__ float acc[512];
    __shared__ float red[256];

    if (attn_out) {
        for (int k = tid; k < 512; k += 256) acc[k] = 0.f;
    }
    const long qrow = (long)bq * D_MODEL;
    const long kbase = (long)b * Nkv * D_MODEL;

    for (int h = 0; h < NHEAD; ++h) {
        if (tid < 64) qs[tid] = Q[qrow + h * 64 + tid];
        __syncthreads();
        // scores
        for (int k = tid; k < Nkv; k += 256) {
            if (causal && k > qi) {
                sc[k] = -INFINITY;
            } else {
                const float* kp = Km + kbase + (long)k * D_MODEL + h * 64;
                float s = 0.f;
                #pragma unroll
                for (int d = 0; d < 64; ++d) s += qs[d] * kp[d];
                sc[k] = s * 0.125f;   // 1/sqrt(64)
            }
        }
        __syncthreads();
        // max
        float m = -INFINITY;
        for (int k = tid; k < Nkv; k += 256) m = fmaxf(m, sc[k]);
        red[tid] = m; __syncthreads();
        for (int s2 = 128; s2 > 0; s2 >>= 1) {
            if (tid < s2) red[tid] = fmaxf(red[tid], red[tid + s2]);
            __syncthreads();
        }
        const float mx = red[0];
        __syncthreads();
        // exp + sum
        float lsum = 0.f;
        for (int k = tid; k < Nkv; k += 256) {
            float e = __expf(sc[k] - mx);
            sc[k] = e;
            lsum += e;
        }
        red[tid] = lsum; __syncthreads();
        for (int s2 = 128; s2 > 0; s2 >>= 1) {
            if (tid < s2) red[tid] += red[tid + s2];
            __syncthreads();
        }
        const float inv = 1.0f / red[0];
        __syncthreads();
        // normalize + accumulate head-mean
        for (int k = tid; k < Nkv; k += 256) {
            float p = sc[k] * inv;
            sc[k] = p;
            if (attn_out) acc[k] += p;
        }
        __syncthreads();
        // O = P @ V : 64 dims x 4 key-groups
        const int d = tid & 63, g = tid >> 6;
        const int kpg = Nkv >> 2;
        float part = 0.f;
        for (int k = g * kpg; k < (g + 1) * kpg; ++k)
            part += sc[k] * Vm[kbase + (long)k * D_MODEL + h * 64 + d];
        red[tid] = part; __syncthreads();
        if (g == 0)
            O[qrow + h * 64 + d] = red[d] + red[d + 64] + red[d + 128] + red[d + 192];
        __syncthreads();
    }

    if (attn_out) {
        float* ao = attn_out + (long)b * Nq * Nkv + (long)qi * Nkv;
        for (int k = tid; k < Nkv; k += 256) ao[k] = acc[k] * 0.125f;  // /H
    }
}

// ---------------------------------------------------------------------------
// LayerNorm: out = LN(X + R1 + R2) * g + b, rows of 512. grid = rows, 256 thr
// ---------------------------------------------------------------------------
__global__ __launch_bounds__(256) void ln_kernel(
    const float* __restrict__ X, const float* __restrict__ R1,
    const float* __restrict__ R2, const float* __restrict__ g,
    const float* __restrict__ bb, float* __restrict__ out)
{
    const long row = blockIdx.x;
    const int tid = threadIdx.x;
    __shared__ float red[256];
    const long base = row * D_MODEL;
    float v0 = X[base + tid], v1 = X[base + tid + 256];
    if (R1) { v0 += R1[base + tid]; v1 += R1[base + tid + 256]; }
    if (R2) { v0 += R2[base + tid]; v1 += R2[base + tid + 256]; }
    red[tid] = v0 + v1; __syncthreads();
    for (int s = 128; s > 0; s >>= 1) {
        if (tid < s) red[tid] += red[tid + s];
        __syncthreads();
    }
    const float mean = red[0] * (1.f / 512.f);
    __syncthreads();
    const float d0 = v0 - mean, d1 = v1 - mean;
    red[tid] = d0 * d0 + d1 * d1; __syncthreads();
    for (int s = 128; s > 0; s >>= 1) {
        if (tid < s) red[tid] += red[tid + s];
        __syncthreads();
    }
    const float rstd = rsqrtf(red[0] * (1.f / 512.f) + 1e-5f);
    out[base + tid]       = d0 * rstd * g[tid] + bb[tid];
    out[base + tid + 256] = d1 * rstd * g[tid + 256] + bb[tid + 256];
}

// ---------------------------------------------------------------------------
// extract last 64 rows per batch: out[b*64+j] = S_base[b*512 + 448 + j]
// ---------------------------------------------------------------------------
__global__ __launch_bounds__(128) void extract_last64(
    const float* __restrict__ S_base, float* __restrict__ out)
{
    const int t = blockIdx.x;          // 0..1023 = b*64 + j
    const int b = t >> 6, j = t & 63;
    const float4* src = (const float4*)(S_base + ((long)b * NSEQ + (NSEQ - LWIN) + j) * D_MODEL);
    float4* dst = (float4*)(out + (long)t * D_MODEL);
    dst[threadIdx.x] = src[threadIdx.x];
}

// ---------------------------------------------------------------------------
// S_local: zeros for n<448, Tloc rows for n>=448. grid = B*N, 128 threads
// ---------------------------------------------------------------------------
__global__ __launch_bounds__(128) void build_slocal(
    const float* __restrict__ Tloc, float* __restrict__ S_local)
{
    const int t = blockIdx.x;           // b*512 + n
    const int b = t >> 9, n = t & 511;
    float4* dst = (float4*)(S_local + (long)t * D_MODEL);
    if (n < NSEQ - LWIN) {
        dst[threadIdx.x] = make_float4(0.f, 0.f, 0.f, 0.f);
    } else {
        const float4* src = (const float4*)(Tloc + ((long)b * LWIN + (n - (NSEQ - LWIN))) * D_MODEL);
        dst[threadIdx.x] = src[threadIdx.x];
    }
}

// ---------------------------------------------------------------------------
// S = a + b + c + d, float4 grid-stride
// ---------------------------------------------------------------------------
__global__ __launch_bounds__(256) void sum4_kernel(
    const float* __restrict__ a, const float* __restrict__ b,
    const float* __restrict__ c, const float* __restrict__ d,
    float* __restrict__ o, int n4)
{
    const int i = blockIdx.x * blockDim.x + threadIdx.x;
    if (i < n4) {
        float4 x = ((const float4*)a)[i];
        float4 y = ((const float4*)b)[i];
        float4 z = ((const float4*)c)[i];
        float4 w = ((const float4*)d)[i];
        ((float4*)o)[i] = make_float4(x.x + y.x + z.x + w.x, x.y + y.y + z.y + w.y,
                                      x.z + y.z + z.z + w.z, x.w + y.w + z.w + w.w);
    }
}

// ---------------------------------------------------------------------------
// pred: p[row] = sigmoid(dot(F[row], pred_w) + pred_b). wave per row.
// grid = rows/4 blocks, 256 threads (4 waves)
// ---------------------------------------------------------------------------
__global__ __launch_bounds__(256) void pred_kernel(
    const float* __restrict__ F, const float* __restrict__ pw,
    const float* __restrict__ pb, float* __restrict__ out)
{
    const int w = threadIdx.x >> 6, lane = threadIdx.x & 63;
    const long row = (long)blockIdx.x * 4 + w;
    const float* fr = F + row * D_MODEL;
    float s = 0.f;
    #pragma unroll
    for (int i = 0; i < 8; ++i) s += fr[lane + i * 64] * pw[lane + i * 64];
    #pragma unroll
    for (int off = 32; off > 0; off >>= 1) s += __shfl_down(s, off);
    if (lane == 0) out[row] = 1.f / (1.f + __expf(-(s + pb[0])));
}

// ---------------------------------------------------------------------------
extern "C" void kernel_launch(void* const* d_in, const int* in_sizes, int n_in,
                              void* d_out, int out_size, void* d_ws, size_t ws_size,
                              hipStream_t stream)
{
    const int*   q          = (const int*)d_in[0];
    const int*   r          = (const int*)d_in[1];
    const int*   qry        = (const int*)d_in[2];
    const float* M_emb      = (const float*)d_in[3];
    const float* E_emb      = (const float*)d_in[4];
    const float* P          = (const float*)d_in[5];
    const float* base_in_w  = (const float*)d_in[6];
    const float* base_in_b  = (const float*)d_in[7];
    const float* base_out_w = (const float*)d_in[8];
    const float* base_out_b = (const float*)d_in[9];
    const float* local_in_w = (const float*)d_in[10];
    const float* local_in_b = (const float*)d_in[11];
    const float* local_out_w= (const float*)d_in[12];
    const float* local_out_b= (const float*)d_in[13];
    const float* glob_in_w  = (const float*)d_in[14];
    const float* glob_in_b  = (const float*)d_in[15];
    const float* glob_out_w = (const float*)d_in[16];
    const float* glob_out_b = (const float*)d_in[17];
    const float* cross_in_w = (const float*)d_in[18];
    const float* cross_in_b = (const float*)d_in[19];
    const float* cross_out_w= (const float*)d_in[20];
    const float* cross_out_b= (const float*)d_in[21];
    const float* ln1_g      = (const float*)d_in[22];
    const float* ln1_b      = (const float*)d_in[23];
    const float* w1         = (const float*)d_in[24];
    const float* b1         = (const float*)d_in[25];
    const float* w2         = (const float*)d_in[26];
    const float* b2         = (const float*)d_in[27];
    const float* ln2_g      = (const float*)d_in[28];
    const float* ln2_b      = (const float*)d_in[29];
    const float* pred_w     = (const float*)d_in[30];
    const float* pred_b     = (const float*)d_in[31];
    float* out = (float*)d_out;

    float* ws = (float*)d_ws;
    const long T = (long)BATCH * NSEQ * D_MODEL;   // 4,194,304 floats
    float* Mbuf   = ws + 0 * T;     // later reused as S_cross
    float* Ebuf   = ws + 1 * T;     // later reused as S_global
    float* Qb     = ws + 2 * T;
    float* Kb     = ws + 3 * T;
    float* Vb     = ws + 4 * T;
    float* Ob     = ws + 5 * T;     // attention out; later S
    float* Tb     = ws + 6 * T;
    float* Sbase  = ws + 7 * T;
    float* Slocal = ws + 8 * T;
    float* Sloc_in = ws + 9 * T;                  // 1024*512
    float* Tloc    = ws + 9 * T + 1024 * 512;     // 1024*512
    float* Sglobal = Ebuf;
    float* Scross  = Mbuf;
    float* Sbuf    = Ob;
    float* H1      = Qb;
    float* Fpre    = Kb;
    float* Fbuf    = Vb;

    const int DD = D_MODEL * D_MODEL;  // weight block stride (rows of in_w)
    dim3 g8k(512 / 64, 8192 / 64);     // N=512, M=8192
    dim3 g1k(512 / 64, 1024 / 64);     // N=512, M=1024

    // ---- embeddings ----
    embed_kernel<<<8192, 128, 0, stream>>>(q, r, qry, M_emb, E_emb, P, Mbuf, Ebuf);

    // ---- base MHA (Q from E, K/V from M, causal) ----
    gemm_xwT<<<g8k, 256, 0, stream>>>(Ebuf, base_in_w,          base_in_b,        Qb, 8192, 512, 512, 0);
    gemm_xwT<<<g8k, 256, 0, stream>>>(Mbuf, base_in_w + DD,     base_in_b + 512,  Kb, 8192, 512, 512, 0);
    gemm_xwT<<<g8k, 256, 0, stream>>>(Mbuf, base_in_w + 2 * DD, base_in_b + 1024, Vb, 8192, 512, 512, 0);
    attn_kernel<<<8192, 256, 0, stream>>>(Qb, Kb, Vb, Ob, out + 8192, 512, 512, 1);
    gemm_xwT<<<g8k, 256, 0, stream>>>(Ob, base_out_w, base_out_b, Tb, 8192, 512, 512, 0);
    ln_kernel<<<8192, 256, 0, stream>>>(Tb, Mbuf, Ebuf, ln1_g, ln1_b, Sbase);

    // ---- local MHA (last 64 tokens, causal) ----
    extract_last64<<<1024, 128, 0, stream>>>(Sbase, Sloc_in);
    gemm_xwT<<<g1k, 256, 0, stream>>>(Sloc_in, local_in_w,          local_in_b,        Qb, 1024, 512, 512, 0);
    gemm_xwT<<<g1k, 256, 0, stream>>>(Sloc_in, local_in_w + DD,     local_in_b + 512,  Kb, 1024, 512, 512, 0);
    gemm_xwT<<<g1k, 256, 0, stream>>>(Sloc_in, local_in_w + 2 * DD, local_in_b + 1024, Vb, 1024, 512, 512, 0);
    attn_kernel<<<1024, 256, 0, stream>>>(Qb, Kb, Vb, Ob, nullptr, 64, 64, 1);
    gemm_xwT<<<g1k, 256, 0, stream>>>(Ob, local_out_w, local_out_b, Tloc, 1024, 512, 512, 0);
    build_slocal<<<8192, 128, 0, stream>>>(Tloc, Slocal);

    // ---- global MHA (S_base self-attn, causal) ----
    gemm_xwT<<<g8k, 256, 0, stream>>>(Sbase, glob_in_w,          glob_in_b,        Qb, 8192, 512, 512, 0);
    gemm_xwT<<<g8k, 256, 0, stream>>>(Sbase, glob_in_w + DD,     glob_in_b + 512,  Kb, 8192, 512, 512, 0);
    gemm_xwT<<<g8k, 256, 0, stream>>>(Sbase, glob_in_w + 2 * DD, glob_in_b + 1024, Vb, 8192, 512, 512, 0);
    attn_kernel<<<8192, 256, 0, stream>>>(Qb, Kb, Vb, Ob, nullptr, 512, 512, 1);
    gemm_xwT<<<g8k, 256, 0, stream>>>(Ob, glob_out_w, glob_out_b, Sglobal, 8192, 512, 512, 0);

    // ---- cross MHA (Q from S_base, K/V from S_local, no mask) ----
    gemm_xwT<<<g8k, 256, 0, stream>>>(Sbase,  cross_in_w,          cross_in_b,        Qb, 8192, 512, 512, 0);
    gemm_xwT<<<g8k, 256, 0, stream>>>(Slocal, cross_in_w + DD,     cross_in_b + 512,  Kb, 8192, 512, 512, 0);
    gemm_xwT<<<g8k, 256, 0, stream>>>(Slocal, cross_in_w + 2 * DD, cross_in_b + 1024, Vb, 8192, 512, 512, 0);
    attn_kernel<<<8192, 256, 0, stream>>>(Qb, Kb, Vb, Ob, nullptr, 512, 512, 0);
    gemm_xwT<<<g8k, 256, 0, stream>>>(Ob, cross_out_w, cross_out_b, Scross, 8192, 512, 512, 0);

    // ---- S = S_base + S_local + S_global + S_cross  (into Ob) ----
    const int n4 = (int)(T / 4);
    sum4_kernel<<<(n4 + 255) / 256, 256, 0, stream>>>(Sbase, Slocal, Sglobal, Scross, Sbuf, n4);

    // ---- FFN + LN2 + pred ----
    gemm_xwT<<<g8k, 256, 0, stream>>>(Sbuf, w1, b1, H1, 8192, 512, 512, 1);
    gemm_xwT<<<g8k, 256, 0, stream>>>(H1, w2, b2, Fpre, 8192, 512, 512, 0);
    ln_kernel<<<8192, 256, 0, stream>>>(Fpre, Sbuf, nullptr, ln2_g, ln2_b, Fbuf);
    pred_kernel<<<2048, 256, 0, stream>>>(Fbuf, pred_w, pred_b, out);
}

// Round 2
// 2055.262 us; speedup vs baseline: 4.2893x; 4.2893x over previous
//
#include <hip/hip_runtime.h>
#include <hip/hip_bf16.h>

#define D_MODEL 512
#define NHEAD 8
#define NSEQ 512
#define BATCH 16
#define LWIN 64

// ---------------------------------------------------------------------------
// embed: M[b,n,:] = M_emb[q + NQ*r] + P[n];  E[b,n,:] = E_emb[qry]
// ---------------------------------------------------------------------------
__global__ __launch_bounds__(128) void embed_kernel(
    const int* __restrict__ q, const int* __restrict__ r, const int* __restrict__ qry,
    const float* __restrict__ M_emb, const float* __restrict__ E_emb,
    const float* __restrict__ P, float* __restrict__ M, float* __restrict__ E)
{
    const int t = blockIdx.x;              // b*N + n
    const int n = t & (NSEQ - 1);
    const int x = q[t] + 10000 * r[t];
    const int e = qry[t];
    const float4* me = (const float4*)(M_emb + (long)x * D_MODEL);
    const float4* pe = (const float4*)(P + (long)n * D_MODEL);
    const float4* ee = (const float4*)(E_emb + (long)e * D_MODEL);
    float4* Mo = (float4*)(M + (long)t * D_MODEL);
    float4* Eo = (float4*)(E + (long)t * D_MODEL);
    const int i = threadIdx.x;
    float4 a = me[i], p4 = pe[i];
    Mo[i] = make_float4(a.x + p4.x, a.y + p4.y, a.z + p4.z, a.w + p4.w);
    Eo[i] = ee[i];
}

// ---------------------------------------------------------------------------
// Generic GEMM: C[M x N] = A[M x K] @ W[N x K]^T + bias[N]  (optional relu)
// ---------------------------------------------------------------------------
__global__ __launch_bounds__(256) void gemm_xwT(
    const float* __restrict__ A, const float* __restrict__ W,
    const float* __restrict__ bias, float* __restrict__ C,
    int M, int N, int K, int relu)
{
    __shared__ float As[16][65];
    __shared__ float Ws[16][65];
    const int tid = threadIdx.x;
    const int n0 = blockIdx.x * 64;
    const int m0 = blockIdx.y * 64;
    const int tx = tid & 15;
    const int ty = tid >> 4;
    const int lrow = tid >> 2;
    const int lk4  = (tid & 3) * 4;

    float c[4][4] = {};

    for (int k0 = 0; k0 < K; k0 += 16) {
        float4 av = *(const float4*)(A + (long)(m0 + lrow) * K + k0 + lk4);
        float4 wv = *(const float4*)(W + (long)(n0 + lrow) * K + k0 + lk4);
        __syncthreads();
        As[lk4 + 0][lrow] = av.x; As[lk4 + 1][lrow] = av.y;
        As[lk4 + 2][lrow] = av.z; As[lk4 + 3][lrow] = av.w;
        Ws[lk4 + 0][lrow] = wv.x; Ws[lk4 + 1][lrow] = wv.y;
        Ws[lk4 + 2][lrow] = wv.z; Ws[lk4 + 3][lrow] = wv.w;
        __syncthreads();
        #pragma unroll
        for (int kk = 0; kk < 16; ++kk) {
            float a0 = As[kk][ty * 4 + 0], a1 = As[kk][ty * 4 + 1];
            float a2 = As[kk][ty * 4 + 2], a3 = As[kk][ty * 4 + 3];
            float b0 = Ws[kk][tx * 4 + 0], b1 = Ws[kk][tx * 4 + 1];
            float b2 = Ws[kk][tx * 4 + 2], b3 = Ws[kk][tx * 4 + 3];
            c[0][0] += a0 * b0; c[0][1] += a0 * b1; c[0][2] += a0 * b2; c[0][3] += a0 * b3;
            c[1][0] += a1 * b0; c[1][1] += a1 * b1; c[1][2] += a1 * b2; c[1][3] += a1 * b3;
            c[2][0] += a2 * b0; c[2][1] += a2 * b1; c[2][2] += a2 * b2; c[2][3] += a2 * b3;
            c[3][0] += a3 * b0; c[3][1] += a3 * b1; c[3][2] += a3 * b2; c[3][3] += a3 * b3;
        }
    }

    float4 bv = *(const float4*)(bias + n0 + tx * 4);
    #pragma unroll
    for (int i = 0; i < 4; ++i) {
        float4 o;
        o.x = c[i][0] + bv.x; o.y = c[i][1] + bv.y;
        o.z = c[i][2] + bv.z; o.w = c[i][3] + bv.w;
        if (relu) {
            o.x = fmaxf(o.x, 0.f); o.y = fmaxf(o.y, 0.f);
            o.z = fmaxf(o.z, 0.f); o.w = fmaxf(o.w, 0.f);
        }
        *(float4*)(C + (long)(m0 + ty * 4 + i) * N + n0 + tx * 4) = o;
    }
}

// ---------------------------------------------------------------------------
// Flash attention: grid (Nq/64, H, B), 256 threads, 4x4 register tile.
// Q,K,V row-major (rows of 512, head h at cols h*64). Online softmax.
// If stats != nullptr, saves per-row (m, l) at stats[((b*H+h)*Nq+q)*2].
// ---------------------------------------------------------------------------
__global__ __launch_bounds__(256) void flash_attn(
    const float* __restrict__ Q, const float* __restrict__ Km,
    const float* __restrict__ Vm, float* __restrict__ O,
    float* __restrict__ stats, int Nq, int Nkv, int causal)
{
    __shared__ __align__(16) float Qst[64][68];  // [dim][q], pre-scaled by 0.125
    __shared__ __align__(16) float KP[64][68];   // Kst [dim][key] -> Pst [key][q]
    __shared__ __align__(16) float Vs[64][68];   // [key][dim]
    __shared__ float red[64][17];
    __shared__ float mrow[64], lrow[64], arow[64];

    const int tid = threadIdx.x;
    const int tx = tid & 15, ty = tid >> 4;
    const int qt = blockIdx.x, h = blockIdx.y, b = blockIdx.z;
    const int rr = tid >> 2, dg = tid & 3;      // staging: row, dim-group

    // stage Q tile transposed, pre-scaled by 1/sqrt(64)
    {
        const float* qsrc = Q + ((long)b * Nq + qt * 64 + rr) * D_MODEL + h * 64;
        #pragma unroll
        for (int s = 0; s < 4; ++s) {
            const int d = s * 16 + dg * 4;
            float4 v = *(const float4*)(qsrc + d);
            Qst[d + 0][rr] = v.x * 0.125f; Qst[d + 1][rr] = v.y * 0.125f;
            Qst[d + 2][rr] = v.z * 0.125f; Qst[d + 3][rr] = v.w * 0.125f;
        }
    }
    if (tid < 64) { mrow[tid] = -INFINITY; lrow[tid] = 0.f; }

    float o[4][4] = {};
    const int nkt = causal ? (qt + 1) : (Nkv >> 6);

    for (int kt = 0; kt < nkt; ++kt) {
        __syncthreads();   // previous tile's PV reads done
        {
            const float* ksrc = Km + ((long)b * Nkv + kt * 64 + rr) * D_MODEL + h * 64;
            const float* vsrc = Vm + ((long)b * Nkv + kt * 64 + rr) * D_MODEL + h * 64;
            #pragma unroll
            for (int s = 0; s < 4; ++s) {
                const int d = s * 16 + dg * 4;
                float4 v = *(const float4*)(ksrc + d);
                KP[d + 0][rr] = v.x; KP[d + 1][rr] = v.y;
                KP[d + 2][rr] = v.z; KP[d + 3][rr] = v.w;
                *(float4*)&Vs[rr][d] = *(const float4*)(vsrc + d);
            }
        }
        __syncthreads();

        // S tile: c[i][j] = sum_kk Qst[kk][ty*4+i] * KP[kk][tx*4+j]
        float c[4][4] = {};
        #pragma unroll 8
        for (int kk = 0; kk < 64; ++kk) {
            float4 aq = *(const float4*)&Qst[kk][ty * 4];
            float4 bk = *(const float4*)&KP[kk][tx * 4];
            float a[4] = {aq.x, aq.y, aq.z, aq.w};
            float bb[4] = {bk.x, bk.y, bk.z, bk.w};
            #pragma unroll
            for (int i = 0; i < 4; ++i)
                #pragma unroll
                for (int j = 0; j < 4; ++j)
                    c[i][j] += a[i] * bb[j];
        }
        if (causal && kt == qt) {
            #pragma unroll
            for (int i = 0; i < 4; ++i)
                #pragma unroll
                for (int j = 0; j < 4; ++j)
                    if (tx * 4 + j > ty * 4 + i) c[i][j] = -INFINITY;
        }
        // row-max partials
        #pragma unroll
        for (int i = 0; i < 4; ++i) {
            float m0 = fmaxf(fmaxf(c[i][0], c[i][1]), fmaxf(c[i][2], c[i][3]));
            red[ty * 4 + i][tx] = m0;
        }
        __syncthreads();   // (A)
        if (tid < 64) {
            float mt = red[tid][0];
            #pragma unroll
            for (int t = 1; t < 16; ++t) mt = fmaxf(mt, red[tid][t]);
            float mo = mrow[tid];
            float mn = fmaxf(mo, mt);
            arow[tid] = __expf(mo - mn);
            mrow[tid] = mn;
        }
        __syncthreads();   // (B)
        #pragma unroll
        for (int i = 0; i < 4; ++i) {
            const int qq = ty * 4 + i;
            const float mm = mrow[qq], aa = arow[qq];
            float rs = 0.f;
            #pragma unroll
            for (int j = 0; j < 4; ++j) {
                float p = __expf(c[i][j] - mm);
                c[i][j] = p; rs += p;
                o[i][j] *= aa;
                KP[tx * 4 + j][qq] = p;    // Pst [key][q] (overlays Kst)
            }
            red[qq][tx] = rs;
        }
        __syncthreads();   // (C)
        if (tid < 64) {
            float s = 0.f;
            #pragma unroll
            for (int t = 0; t < 16; ++t) s += red[tid][t];
            lrow[tid] = lrow[tid] * arow[tid] + s;
        }
        // O += Pst @ Vs
        #pragma unroll 8
        for (int k = 0; k < 64; ++k) {
            float4 pp = *(const float4*)&KP[k][ty * 4];
            float4 vv = *(const float4*)&Vs[k][tx * 4];
            float a[4] = {pp.x, pp.y, pp.z, pp.w};
            float bb[4] = {vv.x, vv.y, vv.z, vv.w};
            #pragma unroll
            for (int i = 0; i < 4; ++i)
                #pragma unroll
                for (int j = 0; j < 4; ++j)
                    o[i][j] += a[i] * bb[j];
        }
    }
    __syncthreads();
    #pragma unroll
    for (int i = 0; i < 4; ++i) {
        const float inv = 1.0f / lrow[ty * 4 + i];
        float4 w;
        w.x = o[i][0] * inv; w.y = o[i][1] * inv;
        w.z = o[i][2] * inv; w.w = o[i][3] * inv;
        *(float4*)(O + ((long)b * Nq + qt * 64 + ty * 4 + i) * D_MODEL + h * 64 + tx * 4) = w;
    }
    if (stats && tid < 64) {
        long idx = (((long)b * NHEAD + h) * Nq + qt * 64 + tid) * 2;
        stats[idx] = mrow[tid]; stats[idx + 1] = lrow[tid];
    }
}

// ---------------------------------------------------------------------------
// attn_w: head-mean base-attention probs via saved (m,l) stats.
// grid (ktile, qtile, b) = (8, 8, 16), 256 threads. Causal (base only).
// ---------------------------------------------------------------------------
__global__ __launch_bounds__(256) void attn_w_kernel(
    const float* __restrict__ Q, const float* __restrict__ Km,
    const float* __restrict__ stats, float* __restrict__ AW)
{
    const int kt = blockIdx.x, qt = blockIdx.y, b = blockIdx.z;
    const int tid = threadIdx.x, tx = tid & 15, ty = tid >> 4;
    if (kt > qt) {   // fully masked tile -> exact zeros (block-uniform branch)
        #pragma unroll
        for (int i = 0; i < 4; ++i)
            *(float4*)(AW + ((long)b * NSEQ + qt * 64 + ty * 4 + i) * NSEQ + kt * 64 + tx * 4)
                = make_float4(0.f, 0.f, 0.f, 0.f);
        return;
    }
    __shared__ __align__(16) float Qst[64][68];
    __shared__ __align__(16) float Kst[64][68];
    __shared__ float mh[64], lih[64];
    const int rr = tid >> 2, dg = tid & 3;
    float acc[4][4] = {};

    for (int h = 0; h < NHEAD; ++h) {
        __syncthreads();
        const float* qsrc = Q + ((long)b * NSEQ + qt * 64 + rr) * D_MODEL + h * 64;
        const float* ksrc = Km + ((long)b * NSEQ + kt * 64 + rr) * D_MODEL + h * 64;
        #pragma unroll
        for (int s = 0; s < 4; ++s) {
            const int d = s * 16 + dg * 4;
            float4 v = *(const float4*)(qsrc + d);
            Qst[d + 0][rr] = v.x * 0.125f; Qst[d + 1][rr] = v.y * 0.125f;
            Qst[d + 2][rr] = v.z * 0.125f; Qst[d + 3][rr] = v.w * 0.125f;
            float4 w = *(const float4*)(ksrc + d);
            Kst[d + 0][rr] = w.x; Kst[d + 1][rr] = w.y;
            Kst[d + 2][rr] = w.z; Kst[d + 3][rr] = w.w;
        }
        if (tid < 64) {
            long idx = (((long)b * NHEAD + h) * NSEQ + qt * 64 + tid) * 2;
            mh[tid] = stats[idx];
            lih[tid] = 1.0f / stats[idx + 1];
        }
        __syncthreads();
        float c[4][4] = {};
        #pragma unroll 8
        for (int kk = 0; kk < 64; ++kk) {
            float4 aq = *(const float4*)&Qst[kk][ty * 4];
            float4 bk = *(const float4*)&Kst[kk][tx * 4];
            float a[4] = {aq.x, aq.y, aq.z, aq.w};
            float bb[4] = {bk.x, bk.y, bk.z, bk.w};
            #pragma unroll
            for (int i = 0; i < 4; ++i)
                #pragma unroll
                for (int j = 0; j < 4; ++j)
                    c[i][j] += a[i] * bb[j];
        }
        #pragma unroll
        for (int i = 0; i < 4; ++i) {
            const float mm = mh[ty * 4 + i], li = lih[ty * 4 + i];
            #pragma unroll
            for (int j = 0; j < 4; ++j) {
                const bool masked = (kt == qt) && (tx * 4 + j > ty * 4 + i);
                if (!masked) acc[i][j] += __expf(c[i][j] - mm) * li;
            }
        }
    }
    #pragma unroll
    for (int i = 0; i < 4; ++i) {
        float4 w;
        w.x = acc[i][0] * 0.125f; w.y = acc[i][1] * 0.125f;
        w.z = acc[i][2] * 0.125f; w.w = acc[i][3] * 0.125f;
        *(float4*)(AW + ((long)b * NSEQ + qt * 64 + ty * 4 + i) * NSEQ + kt * 64 + tx * 4) = w;
    }
}

// ---------------------------------------------------------------------------
// LayerNorm: out = LN(X + R1 + R2) * g + b
// ---------------------------------------------------------------------------
__global__ __launch_bounds__(256) void ln_kernel(
    const float* __restrict__ X, const float* __restrict__ R1,
    const float* __restrict__ R2, const float* __restrict__ g,
    const float* __restrict__ bb, float* __restrict__ out)
{
    const long row = blockIdx.x;
    const int tid = threadIdx.x;
    __shared__ float red[256];
    const long base = row * D_MODEL;
    float v0 = X[base + tid], v1 = X[base + tid + 256];
    if (R1) { v0 += R1[base + tid]; v1 += R1[base + tid + 256]; }
    if (R2) { v0 += R2[base + tid]; v1 += R2[base + tid + 256]; }
    red[tid] = v0 + v1; __syncthreads();
    for (int s = 128; s > 0; s >>= 1) {
        if (tid < s) red[tid] += red[tid + s];
        __syncthreads();
    }
    const float mean = red[0] * (1.f / 512.f);
    __syncthreads();
    const float d0 = v0 - mean, d1 = v1 - mean;
    red[tid] = d0 * d0 + d1 * d1; __syncthreads();
    for (int s = 128; s > 0; s >>= 1) {
        if (tid < s) red[tid] += red[tid + s];
        __syncthreads();
    }
    const float rstd = rsqrtf(red[0] * (1.f / 512.f) + 1e-5f);
    out[base + tid]       = d0 * rstd * g[tid] + bb[tid];
    out[base + tid + 256] = d1 * rstd * g[tid + 256] + bb[tid + 256];
}

__global__ __launch_bounds__(128) void extract_last64(
    const float* __restrict__ S_base, float* __restrict__ out)
{
    const int t = blockIdx.x;          // b*64 + j
    const int b = t >> 6, j = t & 63;
    const float4* src = (const float4*)(S_base + ((long)b * NSEQ + (NSEQ - LWIN) + j) * D_MODEL);
    float4* dst = (float4*)(out + (long)t * D_MODEL);
    dst[threadIdx.x] = src[threadIdx.x];
}

__global__ __launch_bounds__(128) void build_slocal(
    const float* __restrict__ Tloc, float* __restrict__ S_local)
{
    const int t = blockIdx.x;           // b*512 + n
    const int b = t >> 9, n = t & 511;
    float4* dst = (float4*)(S_local + (long)t * D_MODEL);
    if (n < NSEQ - LWIN) {
        dst[threadIdx.x] = make_float4(0.f, 0.f, 0.f, 0.f);
    } else {
        const float4* src = (const float4*)(Tloc + ((long)b * LWIN + (n - (NSEQ - LWIN))) * D_MODEL);
        dst[threadIdx.x] = src[threadIdx.x];
    }
}

__global__ __launch_bounds__(256) void sum4_kernel(
    const float* __restrict__ a, const float* __restrict__ b,
    const float* __restrict__ c, const float* __restrict__ d,
    float* __restrict__ o, int n4)
{
    const int i = blockIdx.x * blockDim.x + threadIdx.x;
    if (i < n4) {
        float4 x = ((const float4*)a)[i];
        float4 y = ((const float4*)b)[i];
        float4 z = ((const float4*)c)[i];
        float4 w = ((const float4*)d)[i];
        ((float4*)o)[i] = make_float4(x.x + y.x + z.x + w.x, x.y + y.y + z.y + w.y,
                                      x.z + y.z + z.z + w.z, x.w + y.w + z.w + w.w);
    }
}

__global__ __launch_bounds__(256) void pred_kernel(
    const float* __restrict__ F, const float* __restrict__ pw,
    const float* __restrict__ pb, float* __restrict__ out)
{
    const int w = threadIdx.x >> 6, lane = threadIdx.x & 63;
    const long row = (long)blockIdx.x * 4 + w;
    const float* fr = F + row * D_MODEL;
    float s = 0.f;
    #pragma unroll
    for (int i = 0; i < 8; ++i) s += fr[lane + i * 64] * pw[lane + i * 64];
    #pragma unroll
    for (int off = 32; off > 0; off >>= 1) s += __shfl_down(s, off);
    if (lane == 0) out[row] = 1.f / (1.f + __expf(-(s + pb[0])));
}

// ---------------------------------------------------------------------------
extern "C" void kernel_launch(void* const* d_in, const int* in_sizes, int n_in,
                              void* d_out, int out_size, void* d_ws, size_t ws_size,
                              hipStream_t stream)
{
    const int*   q          = (const int*)d_in[0];
    const int*   r          = (const int*)d_in[1];
    const int*   qry        = (const int*)d_in[2];
    const float* M_emb      = (const float*)d_in[3];
    const float* E_emb      = (const float*)d_in[4];
    const float* P          = (const float*)d_in[5];
    const float* base_in_w  = (const float*)d_in[6];
    const float* base_in_b  = (const float*)d_in[7];
    const float* base_out_w = (const float*)d_in[8];
    const float* base_out_b = (const float*)d_in[9];
    const float* local_in_w = (const float*)d_in[10];
    const float* local_in_b = (const float*)d_in[11];
    const float* local_out_w= (const float*)d_in[12];
    const float* local_out_b= (const float*)d_in[13];
    const float* glob_in_w  = (const float*)d_in[14];
    const float* glob_in_b  = (const float*)d_in[15];
    const float* glob_out_w = (const float*)d_in[16];
    const float* glob_out_b = (const float*)d_in[17];
    const float* cross_in_w = (const float*)d_in[18];
    const float* cross_in_b = (const float*)d_in[19];
    const float* cross_out_w= (const float*)d_in[20];
    const float* cross_out_b= (const float*)d_in[21];
    const float* ln1_g      = (const float*)d_in[22];
    const float* ln1_b      = (const float*)d_in[23];
    const float* w1         = (const float*)d_in[24];
    const float* b1         = (const float*)d_in[25];
    const float* w2         = (const float*)d_in[26];
    const float* b2         = (const float*)d_in[27];
    const float* ln2_g      = (const float*)d_in[28];
    const float* ln2_b      = (const float*)d_in[29];
    const float* pred_w     = (const float*)d_in[30];
    const float* pred_b     = (const float*)d_in[31];
    float* out = (float*)d_out;

    float* ws = (float*)d_ws;
    const long T = (long)BATCH * NSEQ * D_MODEL;   // 4,194,304 floats
    float* Mbuf   = ws + 0 * T;     // later S_cross
    float* Ebuf   = ws + 1 * T;     // later S_global
    float* Qb     = ws + 2 * T;
    float* Kb     = ws + 3 * T;
    float* Vb     = ws + 4 * T;
    float* Ob     = ws + 5 * T;     // attn out; later S
    float* Tb     = ws + 6 * T;
    float* Sbase  = ws + 7 * T;
    float* Slocal = ws + 8 * T;
    float* Sloc_in = ws + 9 * T;                  // 1024*512 (also stats early)
    float* Tloc    = ws + 9 * T + 1024 * 512;     // 1024*512
    float* stats   = Sloc_in;      // 131072 floats; dead before extract_last64
    float* Sglobal = Ebuf;
    float* Scross  = Mbuf;
    float* Sbuf    = Ob;
    float* H1      = Qb;
    float* Fpre    = Kb;
    float* Fbuf    = Vb;

    const int DD = D_MODEL * D_MODEL;
    dim3 g8k(512 / 64, 8192 / 64);
    dim3 g1k(512 / 64, 1024 / 64);
    dim3 fa_full(8, NHEAD, BATCH);   // qtiles, heads, batch
    dim3 fa_loc(1, NHEAD, BATCH);

    // ---- embeddings ----
    embed_kernel<<<8192, 128, 0, stream>>>(q, r, qry, M_emb, E_emb, P, Mbuf, Ebuf);

    // ---- base MHA (Q from E, K/V from M, causal) + attn_w ----
    gemm_xwT<<<g8k, 256, 0, stream>>>(Ebuf, base_in_w,          base_in_b,        Qb, 8192, 512, 512, 0);
    gemm_xwT<<<g8k, 256, 0, stream>>>(Mbuf, base_in_w + DD,     base_in_b + 512,  Kb, 8192, 512, 512, 0);
    gemm_xwT<<<g8k, 256, 0, stream>>>(Mbuf, base_in_w + 2 * DD, base_in_b + 1024, Vb, 8192, 512, 512, 0);
    flash_attn<<<fa_full, 256, 0, stream>>>(Qb, Kb, Vb, Ob, stats, 512, 512, 1);
    attn_w_kernel<<<dim3(8, 8, BATCH), 256, 0, stream>>>(Qb, Kb, stats, out + 8192);
    gemm_xwT<<<g8k, 256, 0, stream>>>(Ob, base_out_w, base_out_b, Tb, 8192, 512, 512, 0);
    ln_kernel<<<8192, 256, 0, stream>>>(Tb, Mbuf, Ebuf, ln1_g, ln1_b, Sbase);

    // ---- local MHA (last 64 tokens, causal) ----
    extract_last64<<<1024, 128, 0, stream>>>(Sbase, Sloc_in);
    gemm_xwT<<<g1k, 256, 0, stream>>>(Sloc_in, local_in_w,          local_in_b,        Qb, 1024, 512, 512, 0);
    gemm_xwT<<<g1k, 256, 0, stream>>>(Sloc_in, local_in_w + DD,     local_in_b + 512,  Kb, 1024, 512, 512, 0);
    gemm_xwT<<<g1k, 256, 0, stream>>>(Sloc_in, local_in_w + 2 * DD, local_in_b + 1024, Vb, 1024, 512, 512, 0);
    flash_attn<<<fa_loc, 256, 0, stream>>>(Qb, Kb, Vb, Ob, nullptr, 64, 64, 1);
    gemm_xwT<<<g1k, 256, 0, stream>>>(Ob, local_out_w, local_out_b, Tloc, 1024, 512, 512, 0);
    build_slocal<<<8192, 128, 0, stream>>>(Tloc, Slocal);

    // ---- global MHA (S_base self-attn, causal) ----
    gemm_xwT<<<g8k, 256, 0, stream>>>(Sbase, glob_in_w,          glob_in_b,        Qb, 8192, 512, 512, 0);
    gemm_xwT<<<g8k, 256, 0, stream>>>(Sbase, glob_in_w + DD,     glob_in_b + 512,  Kb, 8192, 512, 512, 0);
    gemm_xwT<<<g8k, 256, 0, stream>>>(Sbase, glob_in_w + 2 * DD, glob_in_b + 1024, Vb, 8192, 512, 512, 0);
    flash_attn<<<fa_full, 256, 0, stream>>>(Qb, Kb, Vb, Ob, nullptr, 512, 512, 1);
    gemm_xwT<<<g8k, 256, 0, stream>>>(Ob, glob_out_w, glob_out_b, Sglobal, 8192, 512, 512, 0);

    // ---- cross MHA (Q from S_base, K/V from S_local, no mask) ----
    gemm_xwT<<<g8k, 256, 0, stream>>>(Sbase,  cross_in_w,          cross_in_b,        Qb, 8192, 512, 512, 0);
    gemm_xwT<<<g8k, 256, 0, stream>>>(Slocal, cross_in_w + DD,     cross_in_b + 512,  Kb, 8192, 512, 512, 0);
    gemm_xwT<<<g8k, 256, 0, stream>>>(Slocal, cross_in_w + 2 * DD, cross_in_b + 1024, Vb, 8192, 512, 512, 0);
    flash_attn<<<fa_full, 256, 0, stream>>>(Qb, Kb, Vb, Ob, nullptr, 512, 512, 0);
    gemm_xwT<<<g8k, 256, 0, stream>>>(Ob, cross_out_w, cross_out_b, Scross, 8192, 512, 512, 0);

    // ---- S = S_base + S_local + S_global + S_cross ----
    const int n4 = (int)(T / 4);
    sum4_kernel<<<(n4 + 255) / 256, 256, 0, stream>>>(Sbase, Slocal, Sglobal, Scross, Sbuf, n4);

    // ---- FFN + LN2 + pred ----
    gemm_xwT<<<g8k, 256, 0, stream>>>(Sbuf, w1, b1, H1, 8192, 512, 512, 1);
    gemm_xwT<<<g8k, 256, 0, stream>>>(H1, w2, b2, Fpre, 8192, 512, 512, 0);
    ln_kernel<<<8192, 256, 0, stream>>>(Fpre, Sbuf, nullptr, ln2_g, ln2_b, Fbuf);
    pred_kernel<<<2048, 256, 0, stream>>>(Fbuf, pred_w, pred_b, out);
}

// Round 3
// 934.380 us; speedup vs baseline: 9.4346x; 2.1996x over previous
//
#include <hip/hip_runtime.h>
#include <hip/hip_bf16.h>

#define D_MODEL 512
#define NHEAD 8
#define NSEQ 512
#define BATCH 16
#define LWIN 64

typedef short s16x8 __attribute__((ext_vector_type(8)));
typedef float f32x4 __attribute__((ext_vector_type(4)));

__device__ inline unsigned short f2bf(float f) {
    unsigned int u = __float_as_uint(f);
    u = (u + 0x7fffu + ((u >> 16) & 1u)) >> 16;   // RNE
    return (unsigned short)u;
}
__device__ inline void bf8f(uint4 u, float* f) {
    f[0] = __uint_as_float(u.x << 16); f[1] = __uint_as_float(u.x & 0xffff0000u);
    f[2] = __uint_as_float(u.y << 16); f[3] = __uint_as_float(u.y & 0xffff0000u);
    f[4] = __uint_as_float(u.z << 16); f[5] = __uint_as_float(u.z & 0xffff0000u);
    f[6] = __uint_as_float(u.w << 16); f[7] = __uint_as_float(u.w & 0xffff0000u);
}

// ---------------------------------------------------------------------------
// weight convert: pack 10 fp32 weight matrices into one bf16 region
// order: base_in(786432) local_in glob_in cross_in | base_out(262144)
//        local_out glob_out cross_out w1 w2
// ---------------------------------------------------------------------------
struct WP { const float* p[10]; };
__global__ __launch_bounds__(256) void wconv_kernel(WP wp, unsigned short* __restrict__ Wb)
{
    const long e = ((long)blockIdx.x * 256 + threadIdx.x) * 4;
    const float* src; long loc;
    if (e < 3145728) { int rg = (int)(e / 786432); src = wp.p[rg]; loc = e - (long)rg * 786432; }
    else { long j = e - 3145728; int rg = (int)(j >> 18); src = wp.p[4 + rg]; loc = j - ((long)rg << 18); }
    float4 v = *(const float4*)(src + loc);
    ushort4 o; o.x = f2bf(v.x); o.y = f2bf(v.y); o.z = f2bf(v.z); o.w = f2bf(v.w);
    *(ushort4*)(Wb + e) = o;
}

// ---------------------------------------------------------------------------
// embed: Mf/Mb = M_emb[q+NQ*r]+P ; Ef/Eb = E_emb[qry]   (fp32 + bf16 copies)
// ---------------------------------------------------------------------------
__global__ __launch_bounds__(128) void embed_kernel(
    const int* __restrict__ q, const int* __restrict__ r, const int* __restrict__ qry,
    const float* __restrict__ M_emb, const float* __restrict__ E_emb,
    const float* __restrict__ P, float* __restrict__ Mf, float* __restrict__ Ef,
    unsigned short* __restrict__ Mb, unsigned short* __restrict__ Eb)
{
    const int t = blockIdx.x;              // b*N + n
    const int n = t & (NSEQ - 1);
    const int x = q[t] + 10000 * r[t];
    const int e = qry[t];
    const int i = threadIdx.x;
    float4 a = ((const float4*)(M_emb + (long)x * D_MODEL))[i];
    float4 p4 = ((const float4*)(P + (long)n * D_MODEL))[i];
    float4 ev = ((const float4*)(E_emb + (long)e * D_MODEL))[i];
    float4 mv = make_float4(a.x + p4.x, a.y + p4.y, a.z + p4.z, a.w + p4.w);
    ((float4*)(Mf + (long)t * D_MODEL))[i] = mv;
    ((float4*)(Ef + (long)t * D_MODEL))[i] = ev;
    ushort4 mb; mb.x = f2bf(mv.x); mb.y = f2bf(mv.y); mb.z = f2bf(mv.z); mb.w = f2bf(mv.w);
    ushort4 eb; eb.x = f2bf(ev.x); eb.y = f2bf(ev.y); eb.z = f2bf(ev.z); eb.w = f2bf(ev.w);
    *(ushort4*)(Mb + (long)t * D_MODEL + i * 4) = mb;
    *(ushort4*)(Eb + (long)t * D_MODEL + i * 4) = eb;
}

// ---------------------------------------------------------------------------
// bf16 MFMA GEMM: C[M x N] = A[M x 512] @ W[N x 512]^T + bias
// 128x128 tile, BK=32, 256 thr = 4 waves (2x2 of 64x64), 4x4 mfma 16x16x32.
// grid = (N/128, M/128). Dual output: Cb (bf16) and/or Cf (fp32), stride ldc.
// ---------------------------------------------------------------------------
__global__ __launch_bounds__(256) void gemm_bf16(
    const unsigned short* __restrict__ A, const unsigned short* __restrict__ W,
    const float* __restrict__ bias, unsigned short* __restrict__ Cb,
    float* __restrict__ Cf, int ldc, int relu)
{
    __shared__ unsigned short As[128 * 40];
    __shared__ unsigned short Ws[128 * 40];
    const int tid = threadIdx.x, lane = tid & 63, wid = tid >> 6;
    const int m0 = blockIdx.y * 128, n0 = blockIdx.x * 128;
    const int mbase = (wid >> 1) * 64, nbase = (wid & 1) * 64;
    const int srow = tid >> 2, scol = (tid & 3) * 8;
    const unsigned short* Ap = A + (long)(m0 + srow) * 512 + scol;
    const unsigned short* Wp = W + (long)(n0 + srow) * 512 + scol;
    const int fr = lane & 15;          // fragment row within 16
    const int fk = (lane >> 4) * 8;    // fragment k offset

    f32x4 acc[4][4];
    #pragma unroll
    for (int i = 0; i < 4; ++i)
        #pragma unroll
        for (int j = 0; j < 4; ++j) acc[i][j] = (f32x4){0.f, 0.f, 0.f, 0.f};

    for (int k0 = 0; k0 < 512; k0 += 32) {
        s16x8 a0 = *(const s16x8*)(Ap + k0);
        s16x8 a1 = *(const s16x8*)(Ap + 64 * 512 + k0);
        s16x8 w0 = *(const s16x8*)(Wp + k0);
        s16x8 w1 = *(const s16x8*)(Wp + 64 * 512 + k0);
        __syncthreads();
        *(s16x8*)&As[srow * 40 + scol] = a0;
        *(s16x8*)&As[(64 + srow) * 40 + scol] = a1;
        *(s16x8*)&Ws[srow * 40 + scol] = w0;
        *(s16x8*)&Ws[(64 + srow) * 40 + scol] = w1;
        __syncthreads();
        s16x8 af[4], wf[4];
        #pragma unroll
        for (int t = 0; t < 4; ++t) {
            af[t] = *(const s16x8*)&As[(mbase + t * 16 + fr) * 40 + fk];
            wf[t] = *(const s16x8*)&Ws[(nbase + t * 16 + fr) * 40 + fk];
        }
        #pragma unroll
        for (int i = 0; i < 4; ++i)
            #pragma unroll
            for (int j = 0; j < 4; ++j)
                acc[i][j] = __builtin_amdgcn_mfma_f32_16x16x32_bf16(af[i], wf[j], acc[i][j], 0, 0, 0);
    }

    const int q4 = (lane >> 4) * 4;    // C/D: row = q4+reg, col = fr
    #pragma unroll
    for (int j = 0; j < 4; ++j) {
        const int col = n0 + nbase + j * 16 + fr;
        const float bv = bias[col];
        #pragma unroll
        for (int i = 0; i < 4; ++i) {
            const int row = m0 + mbase + i * 16 + q4;
            #pragma unroll
            for (int rg = 0; rg < 4; ++rg) {
                float v = acc[i][j][rg] + bv;
                if (relu) v = fmaxf(v, 0.f);
                const long off = (long)(row + rg) * ldc + col;
                if (Cb) Cb[off] = f2bf(v);
                if (Cf) Cf[off] = v;
            }
        }
    }
}

// ---------------------------------------------------------------------------
// Flash attention (bf16 in/out): grid (Nq/64, H, B), 256 thr, 4x4 reg tile.
// Q rows stride ldq, K/V rows stride ldkv (head h at col h*64). O stride 512.
// stats != null -> save (m,l) at stats[((b*H+h)*Nq+q)*2].
// ---------------------------------------------------------------------------
__global__ __launch_bounds__(256) void flash_attn(
    const unsigned short* __restrict__ Q, const unsigned short* __restrict__ K,
    const unsigned short* __restrict__ V, unsigned short* __restrict__ O,
    float* __restrict__ stats, int Nq, int Nkv, int ldq, int ldkv, int causal)
{
    __shared__ __align__(16) float Qst[64][68];  // [dim][q], pre-scaled 0.125
    __shared__ __align__(16) float KP[64][68];   // Kst [dim][key] -> Pst [key][q]
    __shared__ __align__(16) float Vs[64][68];   // [key][dim]
    __shared__ float red[64][17];
    __shared__ float mrow[64], lrow[64], arow[64];

    const int tid = threadIdx.x;
    const int tx = tid & 15, ty = tid >> 4;
    const int qt = blockIdx.x, h = blockIdx.y, b = blockIdx.z;

    #pragma unroll
    for (int c = 0; c < 2; ++c) {
        const int flat = c * 256 + tid;
        const int row = flat >> 3, col8 = (flat & 7) * 8;
        uint4 u = *(const uint4*)(Q + ((long)b * Nq + qt * 64 + row) * ldq + h * 64 + col8);
        float f[8]; bf8f(u, f);
        #pragma unroll
        for (int j = 0; j < 8; ++j) Qst[col8 + j][row] = f[j] * 0.125f;
    }
    if (tid < 64) { mrow[tid] = -INFINITY; lrow[tid] = 0.f; }

    float o[4][4] = {};
    const int nkt = causal ? (qt + 1) : (Nkv >> 6);

    for (int kt = 0; kt < nkt; ++kt) {
        __syncthreads();
        #pragma unroll
        for (int c = 0; c < 2; ++c) {
            const int flat = c * 256 + tid;
            const int row = flat >> 3, col8 = (flat & 7) * 8;
            uint4 uk = *(const uint4*)(K + ((long)b * Nkv + kt * 64 + row) * ldkv + h * 64 + col8);
            float fk[8]; bf8f(uk, fk);
            #pragma unroll
            for (int j = 0; j < 8; ++j) KP[col8 + j][row] = fk[j];
            uint4 uv = *(const uint4*)(V + ((long)b * Nkv + kt * 64 + row) * ldkv + h * 64 + col8);
            float fv[8]; bf8f(uv, fv);
            *(float4*)&Vs[row][col8] = make_float4(fv[0], fv[1], fv[2], fv[3]);
            *(float4*)&Vs[row][col8 + 4] = make_float4(fv[4], fv[5], fv[6], fv[7]);
        }
        __syncthreads();

        float c[4][4] = {};
        #pragma unroll 8
        for (int kk = 0; kk < 64; ++kk) {
            float4 aq = *(const float4*)&Qst[kk][ty * 4];
            float4 bk = *(const float4*)&KP[kk][tx * 4];
            float a[4] = {aq.x, aq.y, aq.z, aq.w};
            float bb[4] = {bk.x, bk.y, bk.z, bk.w};
            #pragma unroll
            for (int i = 0; i < 4; ++i)
                #pragma unroll
                for (int j = 0; j < 4; ++j)
                    c[i][j] += a[i] * bb[j];
        }
        if (causal && kt == qt) {
            #pragma unroll
            for (int i = 0; i < 4; ++i)
                #pragma unroll
                for (int j = 0; j < 4; ++j)
                    if (tx * 4 + j > ty * 4 + i) c[i][j] = -INFINITY;
        }
        #pragma unroll
        for (int i = 0; i < 4; ++i)
            red[ty * 4 + i][tx] = fmaxf(fmaxf(c[i][0], c[i][1]), fmaxf(c[i][2], c[i][3]));
        __syncthreads();
        if (tid < 64) {
            float mt = red[tid][0];
            #pragma unroll
            for (int t = 1; t < 16; ++t) mt = fmaxf(mt, red[tid][t]);
            float mo = mrow[tid];
            float mn = fmaxf(mo, mt);
            arow[tid] = __expf(mo - mn);
            mrow[tid] = mn;
        }
        __syncthreads();
        #pragma unroll
        for (int i = 0; i < 4; ++i) {
            const int qq = ty * 4 + i;
            const float mm = mrow[qq], aa = arow[qq];
            float rs = 0.f;
            #pragma unroll
            for (int j = 0; j < 4; ++j) {
                float p = __expf(c[i][j] - mm);
                c[i][j] = p; rs += p;
                o[i][j] *= aa;
                KP[tx * 4 + j][qq] = p;
            }
            red[qq][tx] = rs;
        }
        __syncthreads();
        if (tid < 64) {
            float s = 0.f;
            #pragma unroll
            for (int t = 0; t < 16; ++t) s += red[tid][t];
            lrow[tid] = lrow[tid] * arow[tid] + s;
        }
        #pragma unroll 8
        for (int k = 0; k < 64; ++k) {
            float4 pp = *(const float4*)&KP[k][ty * 4];
            float4 vv = *(const float4*)&Vs[k][tx * 4];
            float a[4] = {pp.x, pp.y, pp.z, pp.w};
            float bb[4] = {vv.x, vv.y, vv.z, vv.w};
            #pragma unroll
            for (int i = 0; i < 4; ++i)
                #pragma unroll
                for (int j = 0; j < 4; ++j)
                    o[i][j] += a[i] * bb[j];
        }
    }
    __syncthreads();
    #pragma unroll
    for (int i = 0; i < 4; ++i) {
        const float inv = 1.0f / lrow[ty * 4 + i];
        ushort4 w4;
        w4.x = f2bf(o[i][0] * inv); w4.y = f2bf(o[i][1] * inv);
        w4.z = f2bf(o[i][2] * inv); w4.w = f2bf(o[i][3] * inv);
        *(ushort4*)(O + ((long)b * Nq + qt * 64 + ty * 4 + i) * D_MODEL + h * 64 + tx * 4) = w4;
    }
    if (stats && tid < 64) {
        long idx = (((long)b * NHEAD + h) * Nq + qt * 64 + tid) * 2;
        stats[idx] = mrow[tid]; stats[idx + 1] = lrow[tid];
    }
}

// ---------------------------------------------------------------------------
// attn_w: head-mean base-attention probs via saved (m,l). grid (8,8,B).
// ---------------------------------------------------------------------------
__global__ __launch_bounds__(256) void attn_w_kernel(
    const unsigned short* __restrict__ Q, const unsigned short* __restrict__ K,
    const float* __restrict__ stats, float* __restrict__ AW, int ldq, int ldk)
{
    const int kt = blockIdx.x, qt = blockIdx.y, b = blockIdx.z;
    const int tid = threadIdx.x, tx = tid & 15, ty = tid >> 4;
    if (kt > qt) {
        #pragma unroll
        for (int i = 0; i < 4; ++i)
            *(float4*)(AW + ((long)b * NSEQ + qt * 64 + ty * 4 + i) * NSEQ + kt * 64 + tx * 4)
                = make_float4(0.f, 0.f, 0.f, 0.f);
        return;
    }
    __shared__ __align__(16) float Qst[64][68];
    __shared__ __align__(16) float Kst[64][68];
    __shared__ float mh[64], lih[64];
    float acc[4][4] = {};

    for (int h = 0; h < NHEAD; ++h) {
        __syncthreads();
        #pragma unroll
        for (int c = 0; c < 2; ++c) {
            const int flat = c * 256 + tid;
            const int row = flat >> 3, col8 = (flat & 7) * 8;
            uint4 uq = *(const uint4*)(Q + ((long)b * NSEQ + qt * 64 + row) * ldq + h * 64 + col8);
            float fq[8]; bf8f(uq, fq);
            #pragma unroll
            for (int j = 0; j < 8; ++j) Qst[col8 + j][row] = fq[j] * 0.125f;
            uint4 uk = *(const uint4*)(K + ((long)b * NSEQ + kt * 64 + row) * ldk + h * 64 + col8);
            float fk[8]; bf8f(uk, fk);
            #pragma unroll
            for (int j = 0; j < 8; ++j) Kst[col8 + j][row] = fk[j];
        }
        if (tid < 64) {
            long idx = (((long)b * NHEAD + h) * NSEQ + qt * 64 + tid) * 2;
            mh[tid] = stats[idx];
            lih[tid] = 1.0f / stats[idx + 1];
        }
        __syncthreads();
        float c[4][4] = {};
        #pragma unroll 8
        for (int kk = 0; kk < 64; ++kk) {
            float4 aq = *(const float4*)&Qst[kk][ty * 4];
            float4 bk = *(const float4*)&Kst[kk][tx * 4];
            float a[4] = {aq.x, aq.y, aq.z, aq.w};
            float bb[4] = {bk.x, bk.y, bk.z, bk.w};
            #pragma unroll
            for (int i = 0; i < 4; ++i)
                #pragma unroll
                for (int j = 0; j < 4; ++j)
                    c[i][j] += a[i] * bb[j];
        }
        #pragma unroll
        for (int i = 0; i < 4; ++i) {
            const float mm = mh[ty * 4 + i], li = lih[ty * 4 + i];
            #pragma unroll
            for (int j = 0; j < 4; ++j) {
                const bool masked = (kt == qt) && (tx * 4 + j > ty * 4 + i);
                if (!masked) acc[i][j] += __expf(c[i][j] - mm) * li;
            }
        }
    }
    #pragma unroll
    for (int i = 0; i < 4; ++i) {
        float4 w;
        w.x = acc[i][0] * 0.125f; w.y = acc[i][1] * 0.125f;
        w.z = acc[i][2] * 0.125f; w.w = acc[i][3] * 0.125f;
        *(float4*)(AW + ((long)b * NSEQ + qt * 64 + ty * 4 + i) * NSEQ + kt * 64 + tx * 4) = w;
    }
}

// ---------------------------------------------------------------------------
// LayerNorm (fp32 in): out = LN(X + R1 + R2)*g + b ; optional bf16 copy
// ---------------------------------------------------------------------------
__global__ __launch_bounds__(256) void ln_kernel(
    const float* __restrict__ X, const float* __restrict__ R1,
    const float* __restrict__ R2, const float* __restrict__ g,
    const float* __restrict__ bb, float* __restrict__ outf,
    unsigned short* __restrict__ outb)
{
    const long row = blockIdx.x;
    const int tid = threadIdx.x;
    __shared__ float red[256];
    const long base = row * D_MODEL;
    float v0 = X[base + tid], v1 = X[base + tid + 256];
    if (R1) { v0 += R1[base + tid]; v1 += R1[base + tid + 256]; }
    if (R2) { v0 += R2[base + tid]; v1 += R2[base + tid + 256]; }
    red[tid] = v0 + v1; __syncthreads();
    for (int s = 128; s > 0; s >>= 1) {
        if (tid < s) red[tid] += red[tid + s];
        __syncthreads();
    }
    const float mean = red[0] * (1.f / 512.f);
    __syncthreads();
    const float d0 = v0 - mean, d1 = v1 - mean;
    red[tid] = d0 * d0 + d1 * d1; __syncthreads();
    for (int s = 128; s > 0; s >>= 1) {
        if (tid < s) red[tid] += red[tid + s];
        __syncthreads();
    }
    const float rstd = rsqrtf(red[0] * (1.f / 512.f) + 1e-5f);
    const float y0 = d0 * rstd * g[tid] + bb[tid];
    const float y1 = d1 * rstd * g[tid + 256] + bb[tid + 256];
    if (outf) { outf[base + tid] = y0; outf[base + tid + 256] = y1; }
    if (outb) { outb[base + tid] = f2bf(y0); outb[base + tid + 256] = f2bf(y1); }
}

// extract last 64 rows per batch from bf16 S_base
__global__ __launch_bounds__(128) void extract_last64(
    const unsigned short* __restrict__ Sb, unsigned short* __restrict__ out)
{
    const int t = blockIdx.x;          // b*64 + j
    const int b = t >> 6, j = t & 63;
    const uint2* src = (const uint2*)(Sb + ((long)b * NSEQ + (NSEQ - LWIN) + j) * D_MODEL);
    uint2* dst = (uint2*)(out + (long)t * D_MODEL);
    dst[threadIdx.x] = src[threadIdx.x];
}

// S_local from Tloc_f: fp32 + bf16 outputs
__global__ __launch_bounds__(128) void build_slocal(
    const float* __restrict__ Tloc, float* __restrict__ Sf, unsigned short* __restrict__ Sb)
{
    const int t = blockIdx.x;           // b*512 + n
    const int b = t >> 9, n = t & 511;
    const int i = threadIdx.x;
    float4 v;
    if (n < NSEQ - LWIN) v = make_float4(0.f, 0.f, 0.f, 0.f);
    else v = ((const float4*)(Tloc + ((long)b * LWIN + (n - (NSEQ - LWIN))) * D_MODEL))[i];
    ((float4*)(Sf + (long)t * D_MODEL))[i] = v;
    ushort4 u; u.x = f2bf(v.x); u.y = f2bf(v.y); u.z = f2bf(v.z); u.w = f2bf(v.w);
    *(ushort4*)(Sb + (long)t * D_MODEL + i * 4) = u;
}

// S = a+b+c+d (fp32) -> fp32 + bf16
__global__ __launch_bounds__(256) void sum4_kernel(
    const float* __restrict__ a, const float* __restrict__ b,
    const float* __restrict__ c, const float* __restrict__ d,
    float* __restrict__ of, unsigned short* __restrict__ ob, int n4)
{
    const int i = blockIdx.x * blockDim.x + threadIdx.x;
    if (i < n4) {
        float4 x = ((const float4*)a)[i];
        float4 y = ((const float4*)b)[i];
        float4 z = ((const float4*)c)[i];
        float4 w = ((const float4*)d)[i];
        float4 s = make_float4(x.x + y.x + z.x + w.x, x.y + y.y + z.y + w.y,
                               x.z + y.z + z.z + w.z, x.w + y.w + z.w + w.w);
        ((float4*)of)[i] = s;
        ushort4 u; u.x = f2bf(s.x); u.y = f2bf(s.y); u.z = f2bf(s.z); u.w = f2bf(s.w);
        *(ushort4*)(ob + (long)i * 4) = u;
    }
}

__global__ __launch_bounds__(256) void pred_kernel(
    const float* __restrict__ F, const float* __restrict__ pw,
    const float* __restrict__ pb, float* __restrict__ out)
{
    const int w = threadIdx.x >> 6, lane = threadIdx.x & 63;
    const long row = (long)blockIdx.x * 4 + w;
    const float* fr = F + row * D_MODEL;
    float s = 0.f;
    #pragma unroll
    for (int i = 0; i < 8; ++i) s += fr[lane + i * 64] * pw[lane + i * 64];
    #pragma unroll
    for (int off = 32; off > 0; off >>= 1) s += __shfl_down(s, off);
    if (lane == 0) out[row] = 1.f / (1.f + __expf(-(s + pb[0])));
}

// ---------------------------------------------------------------------------
extern "C" void kernel_launch(void* const* d_in, const int* in_sizes, int n_in,
                              void* d_out, int out_size, void* d_ws, size_t ws_size,
                              hipStream_t stream)
{
    const int*   q          = (const int*)d_in[0];
    const int*   r          = (const int*)d_in[1];
    const int*   qry        = (const int*)d_in[2];
    const float* M_emb      = (const float*)d_in[3];
    const float* E_emb      = (const float*)d_in[4];
    const float* P          = (const float*)d_in[5];
    const float* base_in_w  = (const float*)d_in[6];
    const float* base_in_b  = (const float*)d_in[7];
    const float* base_out_w = (const float*)d_in[8];
    const float* base_out_b = (const float*)d_in[9];
    const float* local_in_w = (const float*)d_in[10];
    const float* local_in_b = (const float*)d_in[11];
    const float* local_out_w= (const float*)d_in[12];
    const float* local_out_b= (const float*)d_in[13];
    const float* glob_in_w  = (const float*)d_in[14];
    const float* glob_in_b  = (const float*)d_in[15];
    const float* glob_out_w = (const float*)d_in[16];
    const float* glob_out_b = (const float*)d_in[17];
    const float* cross_in_w = (const float*)d_in[18];
    const float* cross_in_b = (const float*)d_in[19];
    const float* cross_out_w= (const float*)d_in[20];
    const float* cross_out_b= (const float*)d_in[21];
    const float* ln1_g      = (const float*)d_in[22];
    const float* ln1_b      = (const float*)d_in[23];
    const float* w1         = (const float*)d_in[24];
    const float* b1         = (const float*)d_in[25];
    const float* w2         = (const float*)d_in[26];
    const float* b2         = (const float*)d_in[27];
    const float* ln2_g      = (const float*)d_in[28];
    const float* ln2_b      = (const float*)d_in[29];
    const float* pred_w     = (const float*)d_in[30];
    const float* pred_b     = (const float*)d_in[31];
    float* out = (float*)d_out;

    // ---- workspace carve-up ----
    char* p = (char*)d_ws;
    unsigned short* Wb = (unsigned short*)p; p += 4718592L * 2;        // 9.44 MB
    unsigned short* B[11];
    for (int i = 0; i < 11; ++i) { B[i] = (unsigned short*)p; p += 8388608L; }  // 8 MB each
    unsigned short* SLin = (unsigned short*)p; p += 1048576L;
    unsigned short* Obl  = (unsigned short*)p; p += 1048576L;
    float* R[5];
    for (int i = 0; i < 5; ++i) { R[i] = (float*)p; p += 16777216L; }
    float* Tloc  = (float*)p; p += 2097152L;
    float* stats = (float*)p; p += 524288L;

    // bf16 buffers
    unsigned short* Mb = B[0];      unsigned short* Qc_b = B[0];
    unsigned short* Eb = B[1];      unsigned short* Oc_b = B[1];
    unsigned short* Qb = B[2];      unsigned short* Sb_b = B[2];
    unsigned short* KVb = B[3];     // spans B[3],B[4]
    unsigned short* Ob  = B[5];     // base attn out; later glob attn out
    unsigned short* Sbase_b  = B[6];
    unsigned short* Slocal_b = B[7];
    unsigned short* QKV3 = B[8];    // spans B[8..10]; later H1
    unsigned short* H1_b = B[8];
    // fp32 buffers
    float* Mf = R[0];       float* Scross_f = R[0];
    float* Ef = R[1];       float* Sbuf_f   = R[1];
    float* Tb_f = R[2];     float* Sglobal_f= R[2];  float* Fbuf_f = R[2];
    float* Sbase_f = R[3];  float* Fpre_f   = R[3];
    float* Slocal_f = R[4];

    // weight sub-offsets in Wb (elements)
    const long oBin = 0, oLin = 786432, oGin = 1572864, oCin = 2359296;
    const long oBout = 3145728, oLout = 3407872, oGout = 3670016, oCout = 3932160;
    const long oW1 = 4194304, oW2 = 4456448;

    dim3 gN512(4, 64), gN1024(8, 64), gN1536(12, 64);
    dim3 gL1536(12, 8), gL512(4, 8);
    dim3 fa_full(8, NHEAD, BATCH), fa_loc(1, NHEAD, BATCH);

    // 0. weights -> bf16
    WP wp; wp.p[0] = base_in_w; wp.p[1] = local_in_w; wp.p[2] = glob_in_w; wp.p[3] = cross_in_w;
    wp.p[4] = base_out_w; wp.p[5] = local_out_w; wp.p[6] = glob_out_w; wp.p[7] = cross_out_w;
    wp.p[8] = w1; wp.p[9] = w2;
    wconv_kernel<<<4608, 256, 0, stream>>>(wp, Wb);

    // 1. embeddings
    embed_kernel<<<8192, 128, 0, stream>>>(q, r, qry, M_emb, E_emb, P, Mf, Ef, Mb, Eb);

    // 2. base MHA: Q = E@Wq, KV = M@Wkv, flash, attn_w, out-proj, ln1
    gemm_bf16<<<gN512, 256, 0, stream>>>(Eb, Wb + oBin, base_in_b, Qb, nullptr, 512, 0);
    gemm_bf16<<<gN1024, 256, 0, stream>>>(Mb, Wb + oBin + 512 * 512, base_in_b + 512, KVb, nullptr, 1024, 0);
    flash_attn<<<fa_full, 256, 0, stream>>>(Qb, KVb, KVb + 512, Ob, stats, 512, 512, 512, 1024, 1);
    attn_w_kernel<<<dim3(8, 8, BATCH), 256, 0, stream>>>(Qb, KVb, stats, out + 8192, 512, 1024);
    gemm_bf16<<<gN512, 256, 0, stream>>>(Ob, Wb + oBout, base_out_b, nullptr, Tb_f, 512, 0);
    ln_kernel<<<8192, 256, 0, stream>>>(Tb_f, Mf, Ef, ln1_g, ln1_b, Sbase_f, Sbase_b);

    // 3. local MHA (last 64 tokens)
    extract_last64<<<1024, 128, 0, stream>>>(Sbase_b, SLin);
    gemm_bf16<<<gL1536, 256, 0, stream>>>(SLin, Wb + oLin, local_in_b, QKV3, nullptr, 1536, 0);
    flash_attn<<<fa_loc, 256, 0, stream>>>(QKV3, QKV3 + 512, QKV3 + 1024, Obl, nullptr, 64, 64, 1536, 1536, 1);
    gemm_bf16<<<gL512, 256, 0, stream>>>(Obl, Wb + oLout, local_out_b, nullptr, Tloc, 512, 0);
    build_slocal<<<8192, 128, 0, stream>>>(Tloc, Slocal_f, Slocal_b);

    // 4. global MHA (S_base self-attn, causal)
    gemm_bf16<<<gN1536, 256, 0, stream>>>(Sbase_b, Wb + oGin, glob_in_b, QKV3, nullptr, 1536, 0);
    flash_attn<<<fa_full, 256, 0, stream>>>(QKV3, QKV3 + 512, QKV3 + 1024, Ob, nullptr, 512, 512, 1536, 1536, 1);
    gemm_bf16<<<gN512, 256, 0, stream>>>(Ob, Wb + oGout, glob_out_b, nullptr, Sglobal_f, 512, 0);

    // 5. cross MHA (Q from S_base, K/V from S_local, no mask)
    gemm_bf16<<<gN512, 256, 0, stream>>>(Sbase_b, Wb + oCin, cross_in_b, Qc_b, nullptr, 512, 0);
    gemm_bf16<<<gN1024, 256, 0, stream>>>(Slocal_b, Wb + oCin + 512 * 512, cross_in_b + 512, KVb, nullptr, 1024, 0);
    flash_attn<<<fa_full, 256, 0, stream>>>(Qc_b, KVb, KVb + 512, Oc_b, nullptr, 512, 512, 512, 1024, 0);
    gemm_bf16<<<gN512, 256, 0, stream>>>(Oc_b, Wb + oCout, cross_out_b, nullptr, Scross_f, 512, 0);

    // 6. S = S_base + S_local + S_global + S_cross
    const int n4 = (int)((long)BATCH * NSEQ * D_MODEL / 4);
    sum4_kernel<<<(n4 + 255) / 256, 256, 0, stream>>>(Sbase_f, Slocal_f, Sglobal_f, Scross_f, Sbuf_f, Sb_b, n4);

    // 7. FFN + LN2 + pred
    gemm_bf16<<<gN512, 256, 0, stream>>>(Sb_b, Wb + oW1, b1, H1_b, nullptr, 512, 1);
    gemm_bf16<<<gN512, 256, 0, stream>>>(H1_b, Wb + oW2, b2, nullptr, Fpre_f, 512, 0);
    ln_kernel<<<8192, 256, 0, stream>>>(Fpre_f, Sbuf_f, nullptr, ln2_g, ln2_b, Fbuf_f, nullptr);
    pred_kernel<<<2048, 256, 0, stream>>>(Fbuf_f, pred_w, pred_b, out);
}

// Round 4
// 582.748 us; speedup vs baseline: 15.1275x; 1.6034x over previous
//
#include <hip/hip_runtime.h>
#include <hip/hip_bf16.h>

#define D_MODEL 512
#define NHEAD 8
#define NSEQ 512
#define BATCH 16
#define LWIN 64

typedef short s16x8 __attribute__((ext_vector_type(8)));
typedef float f32x4 __attribute__((ext_vector_type(4)));

__device__ inline unsigned short f2bf(float f) {
    unsigned int u = __float_as_uint(f);
    u = (u + 0x7fffu + ((u >> 16) & 1u)) >> 16;   // RNE
    return (unsigned short)u;
}

// ---------------------------------------------------------------------------
// weight convert: pack 10 fp32 weight matrices into one bf16 region
// ---------------------------------------------------------------------------
struct WP { const float* p[10]; };
__global__ __launch_bounds__(256) void wconv_kernel(WP wp, unsigned short* __restrict__ Wb)
{
    const long e = ((long)blockIdx.x * 256 + threadIdx.x) * 4;
    const float* src; long loc;
    if (e < 3145728) { int rg = (int)(e / 786432); src = wp.p[rg]; loc = e - (long)rg * 786432; }
    else { long j = e - 3145728; int rg = (int)(j >> 18); src = wp.p[4 + rg]; loc = j - ((long)rg << 18); }
    float4 v = *(const float4*)(src + loc);
    ushort4 o; o.x = f2bf(v.x); o.y = f2bf(v.y); o.z = f2bf(v.z); o.w = f2bf(v.w);
    *(ushort4*)(Wb + e) = o;
}

// ---------------------------------------------------------------------------
// embed: Mf/Mb = M_emb[q+NQ*r]+P ; Ef/Eb = E_emb[qry]   (fp32 + bf16 copies)
// ---------------------------------------------------------------------------
__global__ __launch_bounds__(128) void embed_kernel(
    const int* __restrict__ q, const int* __restrict__ r, const int* __restrict__ qry,
    const float* __restrict__ M_emb, const float* __restrict__ E_emb,
    const float* __restrict__ P, float* __restrict__ Mf, float* __restrict__ Ef,
    unsigned short* __restrict__ Mb, unsigned short* __restrict__ Eb)
{
    const int t = blockIdx.x;              // b*N + n
    const int n = t & (NSEQ - 1);
    const int x = q[t] + 10000 * r[t];
    const int e = qry[t];
    const int i = threadIdx.x;
    float4 a = ((const float4*)(M_emb + (long)x * D_MODEL))[i];
    float4 p4 = ((const float4*)(P + (long)n * D_MODEL))[i];
    float4 ev = ((const float4*)(E_emb + (long)e * D_MODEL))[i];
    float4 mv = make_float4(a.x + p4.x, a.y + p4.y, a.z + p4.z, a.w + p4.w);
    ((float4*)(Mf + (long)t * D_MODEL))[i] = mv;
    ((float4*)(Ef + (long)t * D_MODEL))[i] = ev;
    ushort4 mb; mb.x = f2bf(mv.x); mb.y = f2bf(mv.y); mb.z = f2bf(mv.z); mb.w = f2bf(mv.w);
    ushort4 eb; eb.x = f2bf(ev.x); eb.y = f2bf(ev.y); eb.z = f2bf(ev.z); eb.w = f2bf(ev.w);
    *(ushort4*)(Mb + (long)t * D_MODEL + i * 4) = mb;
    *(ushort4*)(Eb + (long)t * D_MODEL + i * 4) = eb;
}

// ---------------------------------------------------------------------------
// bf16 MFMA GEMM: C[M x N] = A[M x 512] @ W[N x 512]^T + bias
// 128x128 tile, BK=32, 256 thr = 4 waves (2x2 of 64x64), 4x4 mfma 16x16x32.
// ---------------------------------------------------------------------------
__global__ __launch_bounds__(256) void gemm_bf16(
    const unsigned short* __restrict__ A, const unsigned short* __restrict__ W,
    const float* __restrict__ bias, unsigned short* __restrict__ Cb,
    float* __restrict__ Cf, int ldc, int relu)
{
    __shared__ unsigned short As[128 * 40];
    __shared__ unsigned short Ws[128 * 40];
    const int tid = threadIdx.x, lane = tid & 63, wid = tid >> 6;
    const int m0 = blockIdx.y * 128, n0 = blockIdx.x * 128;
    const int mbase = (wid >> 1) * 64, nbase = (wid & 1) * 64;
    const int srow = tid >> 2, scol = (tid & 3) * 8;
    const unsigned short* Ap = A + (long)(m0 + srow) * 512 + scol;
    const unsigned short* Wp = W + (long)(n0 + srow) * 512 + scol;
    const int fr = lane & 15;
    const int fk = (lane >> 4) * 8;

    f32x4 acc[4][4];
    #pragma unroll
    for (int i = 0; i < 4; ++i)
        #pragma unroll
        for (int j = 0; j < 4; ++j) acc[i][j] = (f32x4){0.f, 0.f, 0.f, 0.f};

    for (int k0 = 0; k0 < 512; k0 += 32) {
        s16x8 a0 = *(const s16x8*)(Ap + k0);
        s16x8 a1 = *(const s16x8*)(Ap + 64 * 512 + k0);
        s16x8 w0 = *(const s16x8*)(Wp + k0);
        s16x8 w1 = *(const s16x8*)(Wp + 64 * 512 + k0);
        __syncthreads();
        *(s16x8*)&As[srow * 40 + scol] = a0;
        *(s16x8*)&As[(64 + srow) * 40 + scol] = a1;
        *(s16x8*)&Ws[srow * 40 + scol] = w0;
        *(s16x8*)&Ws[(64 + srow) * 40 + scol] = w1;
        __syncthreads();
        s16x8 af[4], wf[4];
        #pragma unroll
        for (int t = 0; t < 4; ++t) {
            af[t] = *(const s16x8*)&As[(mbase + t * 16 + fr) * 40 + fk];
            wf[t] = *(const s16x8*)&Ws[(nbase + t * 16 + fr) * 40 + fk];
        }
        #pragma unroll
        for (int i = 0; i < 4; ++i)
            #pragma unroll
            for (int j = 0; j < 4; ++j)
                acc[i][j] = __builtin_amdgcn_mfma_f32_16x16x32_bf16(af[i], wf[j], acc[i][j], 0, 0, 0);
    }

    const int q4 = (lane >> 4) * 4;
    #pragma unroll
    for (int j = 0; j < 4; ++j) {
        const int col = n0 + nbase + j * 16 + fr;
        const float bv = bias[col];
        #pragma unroll
        for (int i = 0; i < 4; ++i) {
            const int row = m0 + mbase + i * 16 + q4;
            #pragma unroll
            for (int rg = 0; rg < 4; ++rg) {
                float v = acc[i][j][rg] + bv;
                if (relu) v = fmaxf(v, 0.f);
                const long off = (long)(row + rg) * ldc + col;
                if (Cb) Cb[off] = f2bf(v);
                if (Cf) Cf[off] = v;
            }
        }
    }
}

// ---------------------------------------------------------------------------
// MFMA flash attention: grid (Nq/64, H, B), 256 thr = 4 waves.
// Wave w owns q-rows [w*16, w*16+16); softmax state in registers (shfl_xor
// across the 16 C-layout col-lanes). P round-trips through LDS (own rows only).
// V staged transposed+swizzled for B-frag b128 reads.
// ---------------------------------------------------------------------------
__global__ __launch_bounds__(256) void flash_mfma(
    const unsigned short* __restrict__ Q, const unsigned short* __restrict__ K,
    const unsigned short* __restrict__ V, unsigned short* __restrict__ O,
    float* __restrict__ stats, int Nq, int Nkv, int ldq, int ldkv, int causal)
{
    __shared__ __align__(16) unsigned short Ks[64 * 72];   // [key][dim]
    __shared__ __align__(16) unsigned short Pl[64 * 72];   // [q][key] bf16
    __shared__ __align__(16) unsigned int   Vt[64 * 36];   // [dim][keypair] swizzled

    const int tid = threadIdx.x, lane = tid & 63, w = tid >> 6;
    const int lm = lane & 15, lq = lane >> 4;
    const int qt = blockIdx.x, h = blockIdx.y, b = blockIdx.z;

    // Q A-frags, loaded once from global: m=lm (q-row), k=lq*8+j (+32*ks)
    s16x8 aq0, aq1;
    {
        const unsigned short* qp = Q + ((long)b * Nq + qt * 64 + w * 16 + lm) * ldq + h * 64 + lq * 8;
        aq0 = *(const s16x8*)qp;
        aq1 = *(const s16x8*)(qp + 32);
    }

    float m_r[4] = {-INFINITY, -INFINITY, -INFINITY, -INFINITY};
    float l_r[4] = {0.f, 0.f, 0.f, 0.f};
    f32x4 o_acc[4];
    #pragma unroll
    for (int t = 0; t < 4; ++t) o_acc[t] = (f32x4){0.f, 0.f, 0.f, 0.f};

    const int nkt = causal ? (qt + 1) : (Nkv >> 6);

    for (int kt = 0; kt < nkt; ++kt) {
        __syncthreads();   // prior tile's Ks/Vt reads complete
        // ---- stage K [key][dim], stride 72 ----
        {
            const long kb = ((long)b * Nkv + kt * 64) * ldkv + h * 64;
            #pragma unroll
            for (int c = 0; c < 2; ++c) {
                const int ch = c * 256 + tid;
                const int key = ch >> 3, d = (ch & 7) * 8;
                s16x8 kv = *(const s16x8*)(K + kb + (long)key * ldkv + d);
                *(s16x8*)&Ks[key * 72 + d] = kv;
            }
        }
        // ---- stage V transposed: Vt[dim][kp] = keys (2kp | 2kp+1<<16) ----
        {
            const int kp = tid >> 3, dc = (tid & 7) * 8;
            const unsigned short* vp = V + ((long)b * Nkv + kt * 64 + 2 * kp) * ldkv + h * 64 + dc;
            uint4 va = *(const uint4*)vp;
            uint4 vb = *(const uint4*)(vp + ldkv);
            unsigned pw[8];
            pw[0] = (va.x & 0xffffu) | (vb.x << 16);
            pw[1] = (va.x >> 16)     | (vb.x & 0xffff0000u);
            pw[2] = (va.y & 0xffffu) | (vb.y << 16);
            pw[3] = (va.y >> 16)     | (vb.y & 0xffff0000u);
            pw[4] = (va.z & 0xffffu) | (vb.z << 16);
            pw[5] = (va.z >> 16)     | (vb.z & 0xffff0000u);
            pw[6] = (va.w & 0xffffu) | (vb.w << 16);
            pw[7] = (va.w >> 16)     | (vb.w & 0xffff0000u);
            #pragma unroll
            for (int j = 0; j < 8; ++j) {
                const int row = dc + j;
                const int col = ((((kp >> 2) ^ (row >> 3)) & 7) << 2) | (kp & 3);
                Vt[row * 36 + col] = pw[j];
            }
        }
        __syncthreads();

        // ---- S = Q K^T (C-layout: col=key(lm), row=lq*4+reg) ----
        f32x4 sc[4];
        #pragma unroll
        for (int t = 0; t < 4; ++t) sc[t] = (f32x4){0.f, 0.f, 0.f, 0.f};
        #pragma unroll
        for (int t = 0; t < 4; ++t) {
            s16x8 bk0 = *(const s16x8*)&Ks[(t * 16 + lm) * 72 + lq * 8];
            s16x8 bk1 = *(const s16x8*)&Ks[(t * 16 + lm) * 72 + lq * 8 + 32];
            sc[t] = __builtin_amdgcn_mfma_f32_16x16x32_bf16(aq0, bk0, sc[t], 0, 0, 0);
            sc[t] = __builtin_amdgcn_mfma_f32_16x16x32_bf16(aq1, bk1, sc[t], 0, 0, 0);
        }
        #pragma unroll
        for (int t = 0; t < 4; ++t)
            #pragma unroll
            for (int r = 0; r < 4; ++r) sc[t][r] *= 0.125f;

        if (causal && kt == qt) {
            #pragma unroll
            for (int t = 0; t < 4; ++t)
                #pragma unroll
                for (int r = 0; r < 4; ++r)
                    if (t * 16 + lm > w * 16 + lq * 4 + r) sc[t][r] = -INFINITY;
        }

        // ---- online softmax per owned row (reg r), reduce across 16 lanes ----
        #pragma unroll
        for (int r = 0; r < 4; ++r) {
            float mt = fmaxf(fmaxf(sc[0][r], sc[1][r]), fmaxf(sc[2][r], sc[3][r]));
            #pragma unroll
            for (int off = 1; off < 16; off <<= 1) mt = fmaxf(mt, __shfl_xor(mt, off));
            const float mn = fmaxf(m_r[r], mt);
            const float al = __expf(m_r[r] - mn);
            m_r[r] = mn;
            float rs = 0.f;
            #pragma unroll
            for (int t = 0; t < 4; ++t) {
                float p = __expf(sc[t][r] - mn);
                sc[t][r] = p; rs += p;
                o_acc[t][r] *= al;
                Pl[(w * 16 + lq * 4 + r) * 72 + t * 16 + lm] = f2bf(p);
            }
            #pragma unroll
            for (int off = 1; off < 16; off <<= 1) rs += __shfl_xor(rs, off);
            l_r[r] = l_r[r] * al + rs;
        }

        // ---- O += P @ V (A from Pl own rows, B from Vt) ----
        #pragma unroll
        for (int ks = 0; ks < 2; ++ks) {
            s16x8 ap = *(const s16x8*)&Pl[(w * 16 + lm) * 72 + lq * 8 + ks * 32];
            #pragma unroll
            for (int t = 0; t < 4; ++t) {
                const int row = t * 16 + lm;
                const int gs = ((lq + 4 * ks) ^ (row >> 3)) & 7;
                s16x8 bv = *(const s16x8*)&Vt[row * 36 + gs * 4];
                o_acc[t] = __builtin_amdgcn_mfma_f32_16x16x32_bf16(ap, bv, o_acc[t], 0, 0, 0);
            }
        }
    }

    // ---- epilogue ----
    float inv[4];
    #pragma unroll
    for (int r = 0; r < 4; ++r) inv[r] = 1.0f / l_r[r];
    #pragma unroll
    for (int t = 0; t < 4; ++t)
        #pragma unroll
        for (int r = 0; r < 4; ++r)
            O[((long)b * Nq + qt * 64 + w * 16 + lq * 4 + r) * D_MODEL + h * 64 + t * 16 + lm]
                = f2bf(o_acc[t][r] * inv[r]);
    if (stats && lm == 0) {
        #pragma unroll
        for (int r = 0; r < 4; ++r) {
            const long row = qt * 64 + w * 16 + lq * 4 + r;
            const long idx = (((long)b * NHEAD + h) * Nq + row) * 2;
            stats[idx] = m_r[r]; stats[idx + 1] = l_r[r];
        }
    }
}

// ---------------------------------------------------------------------------
// attn_w (MFMA): head-mean base probs via saved (m,l). grid (8,8,B).
// ---------------------------------------------------------------------------
__global__ __launch_bounds__(256) void attn_w_kernel(
    const unsigned short* __restrict__ Q, const unsigned short* __restrict__ K,
    const float* __restrict__ stats, float* __restrict__ AW, int ldq, int ldk)
{
    const int kt = blockIdx.x, qt = blockIdx.y, b = blockIdx.z;
    const int tid = threadIdx.x;
    if (kt > qt) {
        const int tx = tid & 15, ty = tid >> 4;
        #pragma unroll
        for (int i = 0; i < 4; ++i)
            *(float4*)(AW + ((long)b * NSEQ + qt * 64 + ty * 4 + i) * NSEQ + kt * 64 + tx * 4)
                = make_float4(0.f, 0.f, 0.f, 0.f);
        return;
    }
    __shared__ __align__(16) unsigned short Ks[64 * 72];
    const int lane = tid & 63, w = tid >> 6;
    const int lm = lane & 15, lq = lane >> 4;

    f32x4 aw[4];
    #pragma unroll
    for (int t = 0; t < 4; ++t) aw[t] = (f32x4){0.f, 0.f, 0.f, 0.f};

    for (int h = 0; h < NHEAD; ++h) {
        __syncthreads();
        {
            const long kb = ((long)b * NSEQ + kt * 64) * ldk + h * 64;
            #pragma unroll
            for (int c = 0; c < 2; ++c) {
                const int ch = c * 256 + tid;
                const int key = ch >> 3, d = (ch & 7) * 8;
                s16x8 kv = *(const s16x8*)(K + kb + (long)key * ldk + d);
                *(s16x8*)&Ks[key * 72 + d] = kv;
            }
        }
        __syncthreads();
        s16x8 aq0, aq1;
        {
            const unsigned short* qp = Q + ((long)b * NSEQ + qt * 64 + w * 16 + lm) * ldq + h * 64 + lq * 8;
            aq0 = *(const s16x8*)qp;
            aq1 = *(const s16x8*)(qp + 32);
        }
        f32x4 sc[4];
        #pragma unroll
        for (int t = 0; t < 4; ++t) sc[t] = (f32x4){0.f, 0.f, 0.f, 0.f};
        #pragma unroll
        for (int t = 0; t < 4; ++t) {
            s16x8 bk0 = *(const s16x8*)&Ks[(t * 16 + lm) * 72 + lq * 8];
            s16x8 bk1 = *(const s16x8*)&Ks[(t * 16 + lm) * 72 + lq * 8 + 32];
            sc[t] = __builtin_amdgcn_mfma_f32_16x16x32_bf16(aq0, bk0, sc[t], 0, 0, 0);
            sc[t] = __builtin_amdgcn_mfma_f32_16x16x32_bf16(aq1, bk1, sc[t], 0, 0, 0);
        }
        #pragma unroll
        for (int r = 0; r < 4; ++r) {
            float2 ml = *(const float2*)(stats +
                (((long)b * NHEAD + h) * NSEQ + qt * 64 + w * 16 + lq * 4 + r) * 2);
            const float sub = ml.x, sca = 0.125f / ml.y;
            #pragma unroll
            for (int t = 0; t < 4; ++t) {
                const bool masked = (kt == qt) && (t * 16 + lm > w * 16 + lq * 4 + r);
                if (!masked) aw[t][r] += __expf(sc[t][r] * 0.125f - sub) * sca;
            }
        }
    }
    #pragma unroll
    for (int t = 0; t < 4; ++t)
        #pragma unroll
        for (int r = 0; r < 4; ++r)
            AW[((long)b * NSEQ + qt * 64 + w * 16 + lq * 4 + r) * NSEQ + kt * 64 + t * 16 + lm]
                = aw[t][r];
}

// ---------------------------------------------------------------------------
// LayerNorm (fp32 in): out = LN(X + R1 + R2)*g + b ; optional bf16 copy
// ---------------------------------------------------------------------------
__global__ __launch_bounds__(256) void ln_kernel(
    const float* __restrict__ X, const float* __restrict__ R1,
    const float* __restrict__ R2, const float* __restrict__ g,
    const float* __restrict__ bb, float* __restrict__ outf,
    unsigned short* __restrict__ outb)
{
    const long row = blockIdx.x;
    const int tid = threadIdx.x;
    __shared__ float red[256];
    const long base = row * D_MODEL;
    float v0 = X[base + tid], v1 = X[base + tid + 256];
    if (R1) { v0 += R1[base + tid]; v1 += R1[base + tid + 256]; }
    if (R2) { v0 += R2[base + tid]; v1 += R2[base + tid + 256]; }
    red[tid] = v0 + v1; __syncthreads();
    for (int s = 128; s > 0; s >>= 1) {
        if (tid < s) red[tid] += red[tid + s];
        __syncthreads();
    }
    const float mean = red[0] * (1.f / 512.f);
    __syncthreads();
    const float d0 = v0 - mean, d1 = v1 - mean;
    red[tid] = d0 * d0 + d1 * d1; __syncthreads();
    for (int s = 128; s > 0; s >>= 1) {
        if (tid < s) red[tid] += red[tid + s];
        __syncthreads();
    }
    const float rstd = rsqrtf(red[0] * (1.f / 512.f) + 1e-5f);
    const float y0 = d0 * rstd * g[tid] + bb[tid];
    const float y1 = d1 * rstd * g[tid + 256] + bb[tid + 256];
    if (outf) { outf[base + tid] = y0; outf[base + tid + 256] = y1; }
    if (outb) { outb[base + tid] = f2bf(y0); outb[base + tid + 256] = f2bf(y1); }
}

__global__ __launch_bounds__(128) void extract_last64(
    const unsigned short* __restrict__ Sb, unsigned short* __restrict__ out)
{
    const int t = blockIdx.x;          // b*64 + j
    const int b = t >> 6, j = t & 63;
    const uint2* src = (const uint2*)(Sb + ((long)b * NSEQ + (NSEQ - LWIN) + j) * D_MODEL);
    uint2* dst = (uint2*)(out + (long)t * D_MODEL);
    dst[threadIdx.x] = src[threadIdx.x];
}

__global__ __launch_bounds__(128) void build_slocal(
    const float* __restrict__ Tloc, float* __restrict__ Sf, unsigned short* __restrict__ Sb)
{
    const int t = blockIdx.x;           // b*512 + n
    const int b = t >> 9, n = t & 511;
    const int i = threadIdx.x;
    float4 v;
    if (n < NSEQ - LWIN) v = make_float4(0.f, 0.f, 0.f, 0.f);
    else v = ((const float4*)(Tloc + ((long)b * LWIN + (n - (NSEQ - LWIN))) * D_MODEL))[i];
    ((float4*)(Sf + (long)t * D_MODEL))[i] = v;
    ushort4 u; u.x = f2bf(v.x); u.y = f2bf(v.y); u.z = f2bf(v.z); u.w = f2bf(v.w);
    *(ushort4*)(Sb + (long)t * D_MODEL + i * 4) = u;
}

__global__ __launch_bounds__(256) void sum4_kernel(
    const float* __restrict__ a, const float* __restrict__ b,
    const float* __restrict__ c, const float* __restrict__ d,
    float* __restrict__ of, unsigned short* __restrict__ ob, int n4)
{
    const int i = blockIdx.x * blockDim.x + threadIdx.x;
    if (i < n4) {
        float4 x = ((const float4*)a)[i];
        float4 y = ((const float4*)b)[i];
        float4 z = ((const float4*)c)[i];
        float4 w = ((const float4*)d)[i];
        float4 s = make_float4(x.x + y.x + z.x + w.x, x.y + y.y + z.y + w.y,
                               x.z + y.z + z.z + w.z, x.w + y.w + z.w + w.w);
        ((float4*)of)[i] = s;
        ushort4 u; u.x = f2bf(s.x); u.y = f2bf(s.y); u.z = f2bf(s.z); u.w = f2bf(s.w);
        *(ushort4*)(ob + (long)i * 4) = u;
    }
}

__global__ __launch_bounds__(256) void pred_kernel(
    const float* __restrict__ F, const float* __restrict__ pw,
    const float* __restrict__ pb, float* __restrict__ out)
{
    const int w = threadIdx.x >> 6, lane = threadIdx.x & 63;
    const long row = (long)blockIdx.x * 4 + w;
    const float* fr = F + row * D_MODEL;
    float s = 0.f;
    #pragma unroll
    for (int i = 0; i < 8; ++i) s += fr[lane + i * 64] * pw[lane + i * 64];
    #pragma unroll
    for (int off = 32; off > 0; off >>= 1) s += __shfl_down(s, off);
    if (lane == 0) out[row] = 1.f / (1.f + __expf(-(s + pb[0])));
}

// ---------------------------------------------------------------------------
extern "C" void kernel_launch(void* const* d_in, const int* in_sizes, int n_in,
                              void* d_out, int out_size, void* d_ws, size_t ws_size,
                              hipStream_t stream)
{
    const int*   q          = (const int*)d_in[0];
    const int*   r          = (const int*)d_in[1];
    const int*   qry        = (const int*)d_in[2];
    const float* M_emb      = (const float*)d_in[3];
    const float* E_emb      = (const float*)d_in[4];
    const float* P          = (const float*)d_in[5];
    const float* base_in_w  = (const float*)d_in[6];
    const float* base_in_b  = (const float*)d_in[7];
    const float* base_out_w = (const float*)d_in[8];
    const float* base_out_b = (const float*)d_in[9];
    const float* local_in_w = (const float*)d_in[10];
    const float* local_in_b = (const float*)d_in[11];
    const float* local_out_w= (const float*)d_in[12];
    const float* local_out_b= (const float*)d_in[13];
    const float* glob_in_w  = (const float*)d_in[14];
    const float* glob_in_b  = (const float*)d_in[15];
    const float* glob_out_w = (const float*)d_in[16];
    const float* glob_out_b = (const float*)d_in[17];
    const float* cross_in_w = (const float*)d_in[18];
    const float* cross_in_b = (const float*)d_in[19];
    const float* cross_out_w= (const float*)d_in[20];
    const float* cross_out_b= (const float*)d_in[21];
    const float* ln1_g      = (const float*)d_in[22];
    const float* ln1_b      = (const float*)d_in[23];
    const float* w1         = (const float*)d_in[24];
    const float* b1         = (const float*)d_in[25];
    const float* w2         = (const float*)d_in[26];
    const float* b2         = (const float*)d_in[27];
    const float* ln2_g      = (const float*)d_in[28];
    const float* ln2_b      = (const float*)d_in[29];
    const float* pred_w     = (const float*)d_in[30];
    const float* pred_b     = (const float*)d_in[31];
    float* out = (float*)d_out;

    // ---- workspace carve-up ----
    char* p = (char*)d_ws;
    unsigned short* Wb = (unsigned short*)p; p += 4718592L * 2;        // 9.44 MB
    unsigned short* B[11];
    for (int i = 0; i < 11; ++i) { B[i] = (unsigned short*)p; p += 8388608L; }  // 8 MB each
    unsigned short* SLin = (unsigned short*)p; p += 1048576L;
    unsigned short* Obl  = (unsigned short*)p; p += 1048576L;
    float* R[5];
    for (int i = 0; i < 5; ++i) { R[i] = (float*)p; p += 16777216L; }
    float* Tloc  = (float*)p; p += 2097152L;
    float* stats = (float*)p; p += 524288L;

    // bf16 buffers
    unsigned short* Mb = B[0];      unsigned short* Qc_b = B[0];
    unsigned short* Eb = B[1];      unsigned short* Oc_b = B[1];
    unsigned short* Qb = B[2];      unsigned short* Sb_b = B[2];
    unsigned short* KVb = B[3];     // spans B[3],B[4]
    unsigned short* Ob  = B[5];     // base attn out; later glob attn out
    unsigned short* Sbase_b  = B[6];
    unsigned short* Slocal_b = B[7];
    unsigned short* QKV3 = B[8];    // spans B[8..10]; later H1
    unsigned short* H1_b = B[8];
    // fp32 buffers
    float* Mf = R[0];       float* Scross_f = R[0];
    float* Ef = R[1];       float* Sbuf_f   = R[1];
    float* Tb_f = R[2];     float* Sglobal_f= R[2];  float* Fbuf_f = R[2];
    float* Sbase_f = R[3];  float* Fpre_f   = R[3];
    float* Slocal_f = R[4];

    // weight sub-offsets in Wb (elements)
    const long oBin = 0, oLin = 786432, oGin = 1572864, oCin = 2359296;
    const long oBout = 3145728, oLout = 3407872, oGout = 3670016, oCout = 3932160;
    const long oW1 = 4194304, oW2 = 4456448;

    dim3 gN512(4, 64), gN1024(8, 64), gN1536(12, 64);
    dim3 gL1536(12, 8), gL512(4, 8);
    dim3 fa_full(8, NHEAD, BATCH), fa_loc(1, NHEAD, BATCH);

    // 0. weights -> bf16
    WP wp; wp.p[0] = base_in_w; wp.p[1] = local_in_w; wp.p[2] = glob_in_w; wp.p[3] = cross_in_w;
    wp.p[4] = base_out_w; wp.p[5] = local_out_w; wp.p[6] = glob_out_w; wp.p[7] = cross_out_w;
    wp.p[8] = w1; wp.p[9] = w2;
    wconv_kernel<<<4608, 256, 0, stream>>>(wp, Wb);

    // 1. embeddings
    embed_kernel<<<8192, 128, 0, stream>>>(q, r, qry, M_emb, E_emb, P, Mf, Ef, Mb, Eb);

    // 2. base MHA: Q = E@Wq, KV = M@Wkv, flash, attn_w, out-proj, ln1
    gemm_bf16<<<gN512, 256, 0, stream>>>(Eb, Wb + oBin, base_in_b, Qb, nullptr, 512, 0);
    gemm_bf16<<<gN1024, 256, 0, stream>>>(Mb, Wb + oBin + 512 * 512, base_in_b + 512, KVb, nullptr, 1024, 0);
    flash_mfma<<<fa_full, 256, 0, stream>>>(Qb, KVb, KVb + 512, Ob, stats, 512, 512, 512, 1024, 1);
    attn_w_kernel<<<dim3(8, 8, BATCH), 256, 0, stream>>>(Qb, KVb, stats, out + 8192, 512, 1024);
    gemm_bf16<<<gN512, 256, 0, stream>>>(Ob, Wb + oBout, base_out_b, nullptr, Tb_f, 512, 0);
    ln_kernel<<<8192, 256, 0, stream>>>(Tb_f, Mf, Ef, ln1_g, ln1_b, Sbase_f, Sbase_b);

    // 3. local MHA (last 64 tokens)
    extract_last64<<<1024, 128, 0, stream>>>(Sbase_b, SLin);
    gemm_bf16<<<gL1536, 256, 0, stream>>>(SLin, Wb + oLin, local_in_b, QKV3, nullptr, 1536, 0);
    flash_mfma<<<fa_loc, 256, 0, stream>>>(QKV3, QKV3 + 512, QKV3 + 1024, Obl, nullptr, 64, 64, 1536, 1536, 1);
    gemm_bf16<<<gL512, 256, 0, stream>>>(Obl, Wb + oLout, local_out_b, nullptr, Tloc, 512, 0);
    build_slocal<<<8192, 128, 0, stream>>>(Tloc, Slocal_f, Slocal_b);

    // 4. global MHA (S_base self-attn, causal)
    gemm_bf16<<<gN1536, 256, 0, stream>>>(Sbase_b, Wb + oGin, glob_in_b, QKV3, nullptr, 1536, 0);
    flash_mfma<<<fa_full, 256, 0, stream>>>(QKV3, QKV3 + 512, QKV3 + 1024, Ob, nullptr, 512, 512, 1536, 1536, 1);
    gemm_bf16<<<gN512, 256, 0, stream>>>(Ob, Wb + oGout, glob_out_b, nullptr, Sglobal_f, 512, 0);

    // 5. cross MHA (Q from S_base, K/V from S_local, no mask)
    gemm_bf16<<<gN512, 256, 0, stream>>>(Sbase_b, Wb + oCin, cross_in_b, Qc_b, nullptr, 512, 0);
    gemm_bf16<<<gN1024, 256, 0, stream>>>(Slocal_b, Wb + oCin + 512 * 512, cross_in_b + 512, KVb, nullptr, 1024, 0);
    flash_mfma<<<fa_full, 256, 0, stream>>>(Qc_b, KVb, KVb + 512, Oc_b, nullptr, 512, 512, 512, 1024, 0);
    gemm_bf16<<<gN512, 256, 0, stream>>>(Oc_b, Wb + oCout, cross_out_b, nullptr, Scross_f, 512, 0);

    // 6. S = S_base + S_local + S_global + S_cross
    const int n4 = (int)((long)BATCH * NSEQ * D_MODEL / 4);
    sum4_kernel<<<(n4 + 255) / 256, 256, 0, stream>>>(Sbase_f, Slocal_f, Sglobal_f, Scross_f, Sbuf_f, Sb_b, n4);

    // 7. FFN + LN2 + pred
    gemm_bf16<<<gN512, 256, 0, stream>>>(Sb_b, Wb + oW1, b1, H1_b, nullptr, 512, 1);
    gemm_bf16<<<gN512, 256, 0, stream>>>(H1_b, Wb + oW2, b2, nullptr, Fpre_f, 512, 0);
    ln_kernel<<<8192, 256, 0, stream>>>(Fpre_f, Sbuf_f, nullptr, ln2_g, ln2_b, Fbuf_f, nullptr);
    pred_kernel<<<2048, 256, 0, stream>>>(Fbuf_f, pred_w, pred_b, out);
}

// Round 5
// 534.781 us; speedup vs baseline: 16.4844x; 1.0897x over previous
//
#include <hip/hip_runtime.h>
#include <hip/hip_bf16.h>

#define D_MODEL 512
#define NHEAD 8
#define NSEQ 512
#define BATCH 16
#define LWIN 64
#define S2C 0.18033688f   // 0.125 * log2(e)
#define L2E 1.44269504f

typedef short s16x8 __attribute__((ext_vector_type(8)));
typedef float f32x4 __attribute__((ext_vector_type(4)));

__device__ inline unsigned short f2bf(float f) {
    unsigned int u = __float_as_uint(f);
    u = (u + 0x7fffu + ((u >> 16) & 1u)) >> 16;   // RNE
    return (unsigned short)u;
}

// ---------------------------------------------------------------------------
// weight convert: pack 10 fp32 weight matrices into one bf16 region
// ---------------------------------------------------------------------------
struct WP { const float* p[10]; };
__global__ __launch_bounds__(256) void wconv_kernel(WP wp, unsigned short* __restrict__ Wb)
{
    const long e = ((long)blockIdx.x * 256 + threadIdx.x) * 4;
    const float* src; long loc;
    if (e < 3145728) { int rg = (int)(e / 786432); src = wp.p[rg]; loc = e - (long)rg * 786432; }
    else { long j = e - 3145728; int rg = (int)(j >> 18); src = wp.p[4 + rg]; loc = j - ((long)rg << 18); }
    float4 v = *(const float4*)(src + loc);
    ushort4 o; o.x = f2bf(v.x); o.y = f2bf(v.y); o.z = f2bf(v.z); o.w = f2bf(v.w);
    *(ushort4*)(Wb + e) = o;
}

// ---------------------------------------------------------------------------
// embed: Mf/Mb = M_emb[q+NQ*r]+P ; Ef/Eb = E_emb[qry]   (fp32 + bf16 copies)
// ---------------------------------------------------------------------------
__global__ __launch_bounds__(128) void embed_kernel(
    const int* __restrict__ q, const int* __restrict__ r, const int* __restrict__ qry,
    const float* __restrict__ M_emb, const float* __restrict__ E_emb,
    const float* __restrict__ P, float* __restrict__ Mf, float* __restrict__ Ef,
    unsigned short* __restrict__ Mb, unsigned short* __restrict__ Eb)
{
    const int t = blockIdx.x;              // b*N + n
    const int n = t & (NSEQ - 1);
    const int x = q[t] + 10000 * r[t];
    const int e = qry[t];
    const int i = threadIdx.x;
    float4 a = ((const float4*)(M_emb + (long)x * D_MODEL))[i];
    float4 p4 = ((const float4*)(P + (long)n * D_MODEL))[i];
    float4 ev = ((const float4*)(E_emb + (long)e * D_MODEL))[i];
    float4 mv = make_float4(a.x + p4.x, a.y + p4.y, a.z + p4.z, a.w + p4.w);
    ((float4*)(Mf + (long)t * D_MODEL))[i] = mv;
    ((float4*)(Ef + (long)t * D_MODEL))[i] = ev;
    ushort4 mb; mb.x = f2bf(mv.x); mb.y = f2bf(mv.y); mb.z = f2bf(mv.z); mb.w = f2bf(mv.w);
    ushort4 eb; eb.x = f2bf(ev.x); eb.y = f2bf(ev.y); eb.z = f2bf(ev.z); eb.w = f2bf(ev.w);
    *(ushort4*)(Mb + (long)t * D_MODEL + i * 4) = mb;
    *(ushort4*)(Eb + (long)t * D_MODEL + i * 4) = eb;
}

// ---------------------------------------------------------------------------
// bf16 MFMA GEMM: C[M x N] = Asel[M x 512] @ W[N x 512]^T + bias
// Asel = (n0 >= nsplit) ? A2 : A  (fused QKV with different Q vs K/V inputs).
// arem: A-row remap row -> (row>>6)*512 + 448 + (row&63) (local window gather)
// 128x128 tile, BK=32, 256 thr = 4 waves, 4x4 mfma 16x16x32.
// ---------------------------------------------------------------------------
__global__ __launch_bounds__(256) void gemm_bf16(
    const unsigned short* __restrict__ A, const unsigned short* __restrict__ A2, int nsplit,
    const unsigned short* __restrict__ W, const float* __restrict__ bias,
    unsigned short* __restrict__ Cb, float* __restrict__ Cf, int ldc, int relu, int arem)
{
    __shared__ unsigned short As[128 * 40];
    __shared__ unsigned short Ws[128 * 40];
    const int tid = threadIdx.x, lane = tid & 63, wid = tid >> 6;
    const int m0 = blockIdx.y * 128, n0 = blockIdx.x * 128;
    const int mbase = (wid >> 1) * 64, nbase = (wid & 1) * 64;
    const int srow = tid >> 2, scol = (tid & 3) * 8;
    const unsigned short* Asel = (n0 >= nsplit) ? A2 : A;
    int row0 = m0 + srow, row1 = m0 + srow + 64;
    if (arem) {
        row0 = ((row0 >> 6) << 9) + (NSEQ - LWIN) + (row0 & 63);
        row1 = ((row1 >> 6) << 9) + (NSEQ - LWIN) + (row1 & 63);
    }
    const unsigned short* Ap0 = Asel + (long)row0 * 512 + scol;
    const unsigned short* Ap1 = Asel + (long)row1 * 512 + scol;
    const unsigned short* Wp = W + (long)(n0 + srow) * 512 + scol;
    const int fr = lane & 15;
    const int fk = (lane >> 4) * 8;

    f32x4 acc[4][4];
    #pragma unroll
    for (int i = 0; i < 4; ++i)
        #pragma unroll
        for (int j = 0; j < 4; ++j) acc[i][j] = (f32x4){0.f, 0.f, 0.f, 0.f};

    for (int k0 = 0; k0 < 512; k0 += 32) {
        s16x8 a0 = *(const s16x8*)(Ap0 + k0);
        s16x8 a1 = *(const s16x8*)(Ap1 + k0);
        s16x8 w0 = *(const s16x8*)(Wp + k0);
        s16x8 w1 = *(const s16x8*)(Wp + 64 * 512 + k0);
        __syncthreads();
        *(s16x8*)&As[srow * 40 + scol] = a0;
        *(s16x8*)&As[(64 + srow) * 40 + scol] = a1;
        *(s16x8*)&Ws[srow * 40 + scol] = w0;
        *(s16x8*)&Ws[(64 + srow) * 40 + scol] = w1;
        __syncthreads();
        s16x8 af[4], wf[4];
        #pragma unroll
        for (int t = 0; t < 4; ++t) {
            af[t] = *(const s16x8*)&As[(mbase + t * 16 + fr) * 40 + fk];
            wf[t] = *(const s16x8*)&Ws[(nbase + t * 16 + fr) * 40 + fk];
        }
        #pragma unroll
        for (int i = 0; i < 4; ++i)
            #pragma unroll
            for (int j = 0; j < 4; ++j)
                acc[i][j] = __builtin_amdgcn_mfma_f32_16x16x32_bf16(af[i], wf[j], acc[i][j], 0, 0, 0);
    }

    const int q4 = (lane >> 4) * 4;
    #pragma unroll
    for (int j = 0; j < 4; ++j) {
        const int col = n0 + nbase + j * 16 + fr;
        const float bv = bias[col];
        #pragma unroll
        for (int i = 0; i < 4; ++i) {
            const int row = m0 + mbase + i * 16 + q4;
            #pragma unroll
            for (int rg = 0; rg < 4; ++rg) {
                float v = acc[i][j][rg] + bv;
                if (relu) v = fmaxf(v, 0.f);
                const long off = (long)(row + rg) * ldc + col;
                if (Cb) Cb[off] = f2bf(v);
                if (Cf) Cf[off] = v;
            }
        }
    }
}

// ---------------------------------------------------------------------------
// Transposed MFMA flash attention, paired q-tiles.
// grid (nqt/2 (>=1), H, B), 256 thr = 4 waves. Block handles q-tiles
// qa=blockIdx.x and qb=nqt-1-qa sharing K/V staging (uniform causal work).
// S^T = K Q^T: C col = q -> each lane owns ONE q-row; softmax in-lane +
// 2 shfl_xor. O accumulated transposed. V staged [dim][key] XOR-swizzled.
// ---------------------------------------------------------------------------
__global__ __launch_bounds__(256) void flash_mfma(
    const unsigned short* __restrict__ Q, const unsigned short* __restrict__ K,
    const unsigned short* __restrict__ V, unsigned short* __restrict__ O,
    float* __restrict__ stats, int Nq, int Nkv, int ldq, int ldkv, int causal)
{
    __shared__ __align__(16) unsigned short Ks[64 * 72];   // [key][dim]
    __shared__ __align__(16) unsigned short Pl[64 * 72];   // [q][key] bf16
    __shared__ __align__(16) unsigned int   Vt[64 * 36];   // [dim][keypair] swizzled

    const int tid = threadIdx.x, lane = tid & 63, w = tid >> 6;
    const int lm = lane & 15, lq = lane >> 4;
    const int h = blockIdx.y, b = blockIdx.z;
    const int nqt = Nq >> 6;
    const int qa = blockIdx.x, qb = nqt - 1 - qa;
    const bool single = (qa == qb);

    s16x8 aqA0, aqA1, aqB0, aqB1;
    {
        const unsigned short* qp = Q + ((long)b * Nq + qb * 64 + w * 16 + lm) * ldq + h * 64 + lq * 8;
        aqB0 = *(const s16x8*)qp; aqB1 = *(const s16x8*)(qp + 32);
    }
    if (!single) {
        const unsigned short* qp = Q + ((long)b * Nq + qa * 64 + w * 16 + lm) * ldq + h * 64 + lq * 8;
        aqA0 = *(const s16x8*)qp; aqA1 = *(const s16x8*)(qp + 32);
    }

    float mA = -INFINITY, lA = 0.f, mB = -INFINITY, lB = 0.f;
    f32x4 oA[4], oB[4];
    #pragma unroll
    for (int t = 0; t < 4; ++t) { oA[t] = (f32x4){0.f,0.f,0.f,0.f}; oB[t] = (f32x4){0.f,0.f,0.f,0.f}; }

    const int nkt = causal ? (qb + 1) : (Nkv >> 6);
    const int skey = tid >> 3, sd = (tid & 7) * 8;   // staging coords (K and V)

    s16x8 kr0, kr1; uint4 vr0, vr1;
    {
        const long kb = ((long)b * Nkv) * ldkv + h * 64;
        kr0 = *(const s16x8*)(K + kb + (long)skey * ldkv + sd);
        kr1 = *(const s16x8*)(K + kb + (long)(skey + 32) * ldkv + sd);
        const unsigned short* vp = V + ((long)b * Nkv + 2 * skey) * ldkv + h * 64 + sd;
        vr0 = *(const uint4*)vp; vr1 = *(const uint4*)(vp + ldkv);
    }

    auto process = [&](s16x8 a0, s16x8 a1, float& m, float& l, f32x4* oacc, bool diag) {
        f32x4 sc[4];
        #pragma unroll
        for (int t = 0; t < 4; ++t) sc[t] = (f32x4){0.f,0.f,0.f,0.f};
        #pragma unroll
        for (int t = 0; t < 4; ++t) {
            s16x8 k0 = *(const s16x8*)&Ks[(t * 16 + lm) * 72 + lq * 8];
            s16x8 k1 = *(const s16x8*)&Ks[(t * 16 + lm) * 72 + lq * 8 + 32];
            sc[t] = __builtin_amdgcn_mfma_f32_16x16x32_bf16(k0, a0, sc[t], 0, 0, 0);
            sc[t] = __builtin_amdgcn_mfma_f32_16x16x32_bf16(k1, a1, sc[t], 0, 0, 0);
        }
        if (diag) {
            #pragma unroll
            for (int t = 0; t < 4; ++t)
                #pragma unroll
                for (int r = 0; r < 4; ++r)
                    if (t * 16 + lq * 4 + r > w * 16 + lm) sc[t][r] = -INFINITY;
        }
        float mt = sc[0][0];
        #pragma unroll
        for (int t = 0; t < 4; ++t)
            #pragma unroll
            for (int r = 0; r < 4; ++r) mt = fmaxf(mt, sc[t][r]);
        mt = fmaxf(mt, __shfl_xor(mt, 16));
        mt = fmaxf(mt, __shfl_xor(mt, 32));
        const float mn = fmaxf(m, mt);
        const float al = exp2f((m - mn) * S2C);
        float rs = 0.f;
        #pragma unroll
        for (int t = 0; t < 4; ++t)
            #pragma unroll
            for (int r = 0; r < 4; ++r) {
                float p = exp2f((sc[t][r] - mn) * S2C);
                sc[t][r] = p; rs += p;
            }
        rs += __shfl_xor(rs, 16);
        rs += __shfl_xor(rs, 32);
        m = mn; l = l * al + rs;
        #pragma unroll
        for (int t = 0; t < 4; ++t) oacc[t] *= al;
        #pragma unroll
        for (int t = 0; t < 4; ++t) {
            ushort4 u;
            u.x = f2bf(sc[t][0]); u.y = f2bf(sc[t][1]);
            u.z = f2bf(sc[t][2]); u.w = f2bf(sc[t][3]);
            *(ushort4*)&Pl[(w * 16 + lm) * 72 + t * 16 + lq * 4] = u;
        }
        #pragma unroll
        for (int ks = 0; ks < 2; ++ks) {
            s16x8 bp = *(const s16x8*)&Pl[(w * 16 + lm) * 72 + ks * 32 + lq * 8];
            #pragma unroll
            for (int t = 0; t < 4; ++t) {
                const int row = t * 16 + lm;
                const int pg = ((lq >> 1) + 2 * ks) ^ ((row >> 3) & 3);
                s16x8 av = *(const s16x8*)((const unsigned short*)Vt + row * 72 + pg * 16 + (lq & 1) * 8);
                oacc[t] = __builtin_amdgcn_mfma_f32_16x16x32_bf16(av, bp, oacc[t], 0, 0, 0);
            }
        }
    };

    for (int kt = 0; kt < nkt; ++kt) {
        __syncthreads();
        *(s16x8*)&Ks[skey * 72 + sd] = kr0;
        *(s16x8*)&Ks[(skey + 32) * 72 + sd] = kr1;
        {
            unsigned pw[8];
            pw[0] = (vr0.x & 0xffffu) | (vr1.x << 16);
            pw[1] = (vr0.x >> 16)     | (vr1.x & 0xffff0000u);
            pw[2] = (vr0.y & 0xffffu) | (vr1.y << 16);
            pw[3] = (vr0.y >> 16)     | (vr1.y & 0xffff0000u);
            pw[4] = (vr0.z & 0xffffu) | (vr1.z << 16);
            pw[5] = (vr0.z >> 16)     | (vr1.z & 0xffff0000u);
            pw[6] = (vr0.w & 0xffffu) | (vr1.w << 16);
            pw[7] = (vr0.w >> 16)     | (vr1.w & 0xffff0000u);
            #pragma unroll
            for (int j = 0; j < 8; ++j) {
                const int row = sd + j;
                const int col = (((skey >> 3) ^ ((row >> 3) & 3)) << 3) | (skey & 7);
                Vt[row * 36 + col] = pw[j];
            }
        }
        __syncthreads();
        if (kt + 1 < nkt) {   // register prefetch of next tile
            const long kb = ((long)b * Nkv + (kt + 1) * 64) * ldkv + h * 64;
            kr0 = *(const s16x8*)(K + kb + (long)skey * ldkv + sd);
            kr1 = *(const s16x8*)(K + kb + (long)(skey + 32) * ldkv + sd);
            const unsigned short* vp = V + ((long)b * Nkv + (kt + 1) * 64 + 2 * skey) * ldkv + h * 64 + sd;
            vr0 = *(const uint4*)vp; vr1 = *(const uint4*)(vp + ldkv);
        }
        process(aqB0, aqB1, mB, lB, oB, causal && (kt == qb));
        if (!single && (!causal || kt <= qa))
            process(aqA0, aqA1, mA, lA, oA, causal && (kt == qa));
    }

    // epilogue: O rows (one q per lane), dims t*16+lq*4+r
    {
        const float inv = 1.0f / lB;
        const long orow = ((long)b * Nq + qb * 64 + w * 16 + lm) * D_MODEL + h * 64;
        #pragma unroll
        for (int t = 0; t < 4; ++t) {
            ushort4 u;
            u.x = f2bf(oB[t][0] * inv); u.y = f2bf(oB[t][1] * inv);
            u.z = f2bf(oB[t][2] * inv); u.w = f2bf(oB[t][3] * inv);
            *(ushort4*)(O + orow + t * 16 + lq * 4) = u;
        }
    }
    if (!single) {
        const float inv = 1.0f / lA;
        const long orow = ((long)b * Nq + qa * 64 + w * 16 + lm) * D_MODEL + h * 64;
        #pragma unroll
        for (int t = 0; t < 4; ++t) {
            ushort4 u;
            u.x = f2bf(oA[t][0] * inv); u.y = f2bf(oA[t][1] * inv);
            u.z = f2bf(oA[t][2] * inv); u.w = f2bf(oA[t][3] * inv);
            *(ushort4*)(O + orow + t * 16 + lq * 4) = u;
        }
    }
    if (stats && lq == 0) {
        long idx = (((long)b * NHEAD + h) * Nq + qb * 64 + w * 16 + lm) * 2;
        stats[idx] = mB * 0.125f; stats[idx + 1] = lB;
        if (!single) {
            idx = (((long)b * NHEAD + h) * Nq + qa * 64 + w * 16 + lm) * 2;
            stats[idx] = mA * 0.125f; stats[idx + 1] = lA;
        }
    }
}

// ---------------------------------------------------------------------------
// attn_w (transposed MFMA): head-mean base probs via saved (m,l). grid (8,8,B).
// ---------------------------------------------------------------------------
__global__ __launch_bounds__(256) void attn_w_kernel(
    const unsigned short* __restrict__ Q, const unsigned short* __restrict__ K,
    const float* __restrict__ stats, float* __restrict__ AW, int ldq, int ldk)
{
    const int kt = blockIdx.x, qt = blockIdx.y, b = blockIdx.z;
    const int tid = threadIdx.x;
    if (kt > qt) {
        const int tx = tid & 15, ty = tid >> 4;
        #pragma unroll
        for (int i = 0; i < 4; ++i)
            *(float4*)(AW + ((long)b * NSEQ + qt * 64 + ty * 4 + i) * NSEQ + kt * 64 + tx * 4)
                = make_float4(0.f, 0.f, 0.f, 0.f);
        return;
    }
    __shared__ __align__(16) unsigned short Ks[64 * 72];
    const int lane = tid & 63, w = tid >> 6;
    const int lm = lane & 15, lq = lane >> 4;
    const int skey = tid >> 3, sd = (tid & 7) * 8;
    const long qrow = (long)b * NSEQ + qt * 64 + w * 16 + lm;

    f32x4 aw[4];
    #pragma unroll
    for (int t = 0; t < 4; ++t) aw[t] = (f32x4){0.f,0.f,0.f,0.f};

    for (int h = 0; h < NHEAD; ++h) {
        __syncthreads();
        {
            const long kb = ((long)b * NSEQ + kt * 64) * ldk + h * 64;
            *(s16x8*)&Ks[skey * 72 + sd] = *(const s16x8*)(K + kb + (long)skey * ldk + sd);
            *(s16x8*)&Ks[(skey + 32) * 72 + sd] = *(const s16x8*)(K + kb + (long)(skey + 32) * ldk + sd);
        }
        __syncthreads();
        s16x8 a0, a1;
        {
            const unsigned short* qp = Q + qrow * ldq + h * 64 + lq * 8;
            a0 = *(const s16x8*)qp; a1 = *(const s16x8*)(qp + 32);
        }
        f32x4 sc[4];
        #pragma unroll
        for (int t = 0; t < 4; ++t) sc[t] = (f32x4){0.f,0.f,0.f,0.f};
        #pragma unroll
        for (int t = 0; t < 4; ++t) {
            s16x8 k0 = *(const s16x8*)&Ks[(t * 16 + lm) * 72 + lq * 8];
            s16x8 k1 = *(const s16x8*)&Ks[(t * 16 + lm) * 72 + lq * 8 + 32];
            sc[t] = __builtin_amdgcn_mfma_f32_16x16x32_bf16(k0, a0, sc[t], 0, 0, 0);
            sc[t] = __builtin_amdgcn_mfma_f32_16x16x32_bf16(k1, a1, sc[t], 0, 0, 0);
        }
        float2 ml = *(const float2*)(stats + (((long)b * NHEAD + h) * NSEQ + qt * 64 + w * 16 + lm) * 2);
        const float mb2 = ml.x * L2E;
        const float sca = 0.125f / ml.y;
        #pragma unroll
        for (int t = 0; t < 4; ++t)
            #pragma unroll
            for (int r = 0; r < 4; ++r) {
                const bool masked = (kt == qt) && (t * 16 + lq * 4 + r > w * 16 + lm);
                if (!masked) aw[t][r] += exp2f(sc[t][r] * S2C - mb2) * sca;
            }
    }
    #pragma unroll
    for (int t = 0; t < 4; ++t)
        *(float4*)(AW + qrow * NSEQ + kt * 64 + t * 16 + lq * 4) = float4{aw[t][0], aw[t][1], aw[t][2], aw[t][3]};
}

// ---------------------------------------------------------------------------
// LayerNorm (fp32 in): out = LN(X + R1 + R2)*g + b ; optional bf16 copy
// ---------------------------------------------------------------------------
__global__ __launch_bounds__(256) void ln_kernel(
    const float* __restrict__ X, const float* __restrict__ R1,
    const float* __restrict__ R2, const float* __restrict__ g,
    const float* __restrict__ bb, float* __restrict__ outf,
    unsigned short* __restrict__ outb)
{
    const long row = blockIdx.x;
    const int tid = threadIdx.x;
    __shared__ float red[256];
    const long base = row * D_MODEL;
    float v0 = X[base + tid], v1 = X[base + tid + 256];
    if (R1) { v0 += R1[base + tid]; v1 += R1[base + tid + 256]; }
    if (R2) { v0 += R2[base + tid]; v1 += R2[base + tid + 256]; }
    red[tid] = v0 + v1; __syncthreads();
    for (int s = 128; s > 0; s >>= 1) {
        if (tid < s) red[tid] += red[tid + s];
        __syncthreads();
    }
    const float mean = red[0] * (1.f / 512.f);
    __syncthreads();
    const float d0 = v0 - mean, d1 = v1 - mean;
    red[tid] = d0 * d0 + d1 * d1; __syncthreads();
    for (int s = 128; s > 0; s >>= 1) {
        if (tid < s) red[tid] += red[tid + s];
        __syncthreads();
    }
    const float rstd = rsqrtf(red[0] * (1.f / 512.f) + 1e-5f);
    const float y0 = d0 * rstd * g[tid] + bb[tid];
    const float y1 = d1 * rstd * g[tid + 256] + bb[tid + 256];
    if (outf) { outf[base + tid] = y0; outf[base + tid + 256] = y1; }
    if (outb) { outb[base + tid] = f2bf(y0); outb[base + tid + 256] = f2bf(y1); }
}

__global__ __launch_bounds__(128) void build_slocal(
    const float* __restrict__ Tloc, float* __restrict__ Sf, unsigned short* __restrict__ Sb)
{
    const int t = blockIdx.x;           // b*512 + n
    const int b = t >> 9, n = t & 511;
    const int i = threadIdx.x;
    float4 v;
    if (n < NSEQ - LWIN) v = make_float4(0.f, 0.f, 0.f, 0.f);
    else v = ((const float4*)(Tloc + ((long)b * LWIN + (n - (NSEQ - LWIN))) * D_MODEL))[i];
    ((float4*)(Sf + (long)t * D_MODEL))[i] = v;
    ushort4 u; u.x = f2bf(v.x); u.y = f2bf(v.y); u.z = f2bf(v.z); u.w = f2bf(v.w);
    *(ushort4*)(Sb + (long)t * D_MODEL + i * 4) = u;
}

__global__ __launch_bounds__(256) void sum4_kernel(
    const float* __restrict__ a, const float* __restrict__ b,
    const float* __restrict__ c, const float* __restrict__ d,
    float* __restrict__ of, unsigned short* __restrict__ ob, int n4)
{
    const int i = blockIdx.x * blockDim.x + threadIdx.x;
    if (i < n4) {
        float4 x = ((const float4*)a)[i];
        float4 y = ((const float4*)b)[i];
        float4 z = ((const float4*)c)[i];
        float4 w = ((const float4*)d)[i];
        float4 s = make_float4(x.x + y.x + z.x + w.x, x.y + y.y + z.y + w.y,
                               x.z + y.z + z.z + w.z, x.w + y.w + z.w + w.w);
        ((float4*)of)[i] = s;
        ushort4 u; u.x = f2bf(s.x); u.y = f2bf(s.y); u.z = f2bf(s.z); u.w = f2bf(s.w);
        *(ushort4*)(ob + (long)i * 4) = u;
    }
}

__global__ __launch_bounds__(256) void pred_kernel(
    const float* __restrict__ F, const float* __restrict__ pw,
    const float* __restrict__ pb, float* __restrict__ out)
{
    const int w = threadIdx.x >> 6, lane = threadIdx.x & 63;
    const long row = (long)blockIdx.x * 4 + w;
    const float* fr = F + row * D_MODEL;
    float s = 0.f;
    #pragma unroll
    for (int i = 0; i < 8; ++i) s += fr[lane + i * 64] * pw[lane + i * 64];
    #pragma unroll
    for (int off = 32; off > 0; off >>= 1) s += __shfl_down(s, off);
    if (lane == 0) out[row] = 1.f / (1.f + __expf(-(s + pb[0])));
}

// ---------------------------------------------------------------------------
extern "C" void kernel_launch(void* const* d_in, const int* in_sizes, int n_in,
                              void* d_out, int out_size, void* d_ws, size_t ws_size,
                              hipStream_t stream)
{
    const int*   q          = (const int*)d_in[0];
    const int*   r          = (const int*)d_in[1];
    const int*   qry        = (const int*)d_in[2];
    const float* M_emb      = (const float*)d_in[3];
    const float* E_emb      = (const float*)d_in[4];
    const float* P          = (const float*)d_in[5];
    const float* base_in_w  = (const float*)d_in[6];
    const float* base_in_b  = (const float*)d_in[7];
    const float* base_out_w = (const float*)d_in[8];
    const float* base_out_b = (const float*)d_in[9];
    const float* local_in_w = (const float*)d_in[10];
    const float* local_in_b = (const float*)d_in[11];
    const float* local_out_w= (const float*)d_in[12];
    const float* local_out_b= (const float*)d_in[13];
    const float* glob_in_w  = (const float*)d_in[14];
    const float* glob_in_b  = (const float*)d_in[15];
    const float* glob_out_w = (const float*)d_in[16];
    const float* glob_out_b = (const float*)d_in[17];
    const float* cross_in_w = (const float*)d_in[18];
    const float* cross_in_b = (const float*)d_in[19];
    const float* cross_out_w= (const float*)d_in[20];
    const float* cross_out_b= (const float*)d_in[21];
    const float* ln1_g      = (const float*)d_in[22];
    const float* ln1_b      = (const float*)d_in[23];
    const float* w1         = (const float*)d_in[24];
    const float* b1         = (const float*)d_in[25];
    const float* w2         = (const float*)d_in[26];
    const float* b2         = (const float*)d_in[27];
    const float* ln2_g      = (const float*)d_in[28];
    const float* ln2_b      = (const float*)d_in[29];
    const float* pred_w     = (const float*)d_in[30];
    const float* pred_b     = (const float*)d_in[31];
    float* out = (float*)d_out;

    // ---- workspace carve-up ----
    char* p = (char*)d_ws;
    unsigned short* Wb = (unsigned short*)p; p += 4718592L * 2;        // 9.44 MB
    unsigned short* B[11];
    for (int i = 0; i < 11; ++i) { B[i] = (unsigned short*)p; p += 8388608L; }  // 8 MB each
    unsigned short* Obl  = (unsigned short*)p; p += 1048576L;
    float* R[5];
    for (int i = 0; i < 5; ++i) { R[i] = (float*)p; p += 16777216L; }
    float* Tloc  = (float*)p; p += 2097152L;
    float* stats = (float*)p; p += 524288L;

    // bf16 buffers
    unsigned short* Mb = B[0];
    unsigned short* Eb = B[1];      unsigned short* Oc_b = B[1];
    unsigned short* QKVb = B[2];    // base QKV (spans B[2..4]); later cross QKV; later Sb_b
    unsigned short* Sb_b = B[2];
    unsigned short* Ob  = B[5];     // base attn out; later glob attn out
    unsigned short* Sbase_b  = B[6];
    unsigned short* Slocal_b = B[7];
    unsigned short* QKV3 = B[8];    // local QKV, then glob QKV (spans B[8..10]); later H1
    unsigned short* H1_b = B[8];
    // fp32 buffers
    float* Mf = R[0];       float* Scross_f = R[0];
    float* Ef = R[1];       float* Sbuf_f   = R[1];
    float* Tb_f = R[2];     float* Sglobal_f= R[2];  float* Fbuf_f = R[2];
    float* Sbase_f = R[3];  float* Fpre_f   = R[3];
    float* Slocal_f = R[4];

    // weight sub-offsets in Wb (elements)
    const long oBin = 0, oLin = 786432, oGin = 1572864, oCin = 2359296;
    const long oBout = 3145728, oLout = 3407872, oGout = 3670016, oCout = 3932160;
    const long oW1 = 4194304, oW2 = 4456448;
    const int BIG = 1 << 30;

    dim3 gN512(4, 64), gN1536(12, 64);
    dim3 gL1536(12, 8), gL512(4, 8);
    dim3 fa_full(4, NHEAD, BATCH), fa_loc(1, NHEAD, BATCH);

    // 0. weights -> bf16
    WP wp; wp.p[0] = base_in_w; wp.p[1] = local_in_w; wp.p[2] = glob_in_w; wp.p[3] = cross_in_w;
    wp.p[4] = base_out_w; wp.p[5] = local_out_w; wp.p[6] = glob_out_w; wp.p[7] = cross_out_w;
    wp.p[8] = w1; wp.p[9] = w2;
    wconv_kernel<<<4608, 256, 0, stream>>>(wp, Wb);

    // 1. embeddings
    embed_kernel<<<8192, 128, 0, stream>>>(q, r, qry, M_emb, E_emb, P, Mf, Ef, Mb, Eb);

    // 2. base MHA: fused QKV (Q from E, K/V from M), flash, attn_w, out-proj, ln1
    gemm_bf16<<<gN1536, 256, 0, stream>>>(Eb, Mb, 512, Wb + oBin, base_in_b, QKVb, nullptr, 1536, 0, 0);
    flash_mfma<<<fa_full, 256, 0, stream>>>(QKVb, QKVb + 512, QKVb + 1024, Ob, stats, 512, 512, 1536, 1536, 1);
    attn_w_kernel<<<dim3(8, 8, BATCH), 256, 0, stream>>>(QKVb, QKVb + 512, stats, out + 8192, 1536, 1536);
    gemm_bf16<<<gN512, 256, 0, stream>>>(Ob, Ob, BIG, Wb + oBout, base_out_b, nullptr, Tb_f, 512, 0, 0);
    ln_kernel<<<8192, 256, 0, stream>>>(Tb_f, Mf, Ef, ln1_g, ln1_b, Sbase_f, Sbase_b);

    // 3. local MHA (last 64 tokens; A-row remap replaces extract)
    gemm_bf16<<<gL1536, 256, 0, stream>>>(Sbase_b, Sbase_b, BIG, Wb + oLin, local_in_b, QKV3, nullptr, 1536, 0, 1);
    flash_mfma<<<fa_loc, 256, 0, stream>>>(QKV3, QKV3 + 512, QKV3 + 1024, Obl, nullptr, 64, 64, 1536, 1536, 1);
    gemm_bf16<<<gL512, 256, 0, stream>>>(Obl, Obl, BIG, Wb + oLout, local_out_b, nullptr, Tloc, 512, 0, 0);
    build_slocal<<<8192, 128, 0, stream>>>(Tloc, Slocal_f, Slocal_b);

    // 4. global MHA (S_base self-attn, causal)
    gemm_bf16<<<gN1536, 256, 0, stream>>>(Sbase_b, Sbase_b, BIG, Wb + oGin, glob_in_b, QKV3, nullptr, 1536, 0, 0);
    flash_mfma<<<fa_full, 256, 0, stream>>>(QKV3, QKV3 + 512, QKV3 + 1024, Ob, nullptr, 512, 512, 1536, 1536, 1);
    gemm_bf16<<<gN512, 256, 0, stream>>>(Ob, Ob, BIG, Wb + oGout, glob_out_b, nullptr, Sglobal_f, 512, 0, 0);

    // 5. cross MHA (Q from S_base, K/V from S_local, no mask) — fused QKV
    gemm_bf16<<<gN1536, 256, 0, stream>>>(Sbase_b, Slocal_b, 512, Wb + oCin, cross_in_b, QKVb, nullptr, 1536, 0, 0);
    flash_mfma<<<fa_full, 256, 0, stream>>>(QKVb, QKVb + 512, QKVb + 1024, Oc_b, nullptr, 512, 512, 1536, 1536, 0);
    gemm_bf16<<<gN512, 256, 0, stream>>>(Oc_b, Oc_b, BIG, Wb + oCout, cross_out_b, nullptr, Scross_f, 512, 0, 0);

    // 6. S = S_base + S_local + S_global + S_cross
    const int n4 = (int)((long)BATCH * NSEQ * D_MODEL / 4);
    sum4_kernel<<<(n4 + 255) / 256, 256, 0, stream>>>(Sbase_f, Slocal_f, Sglobal_f, Scross_f, Sbuf_f, Sb_b, n4);

    // 7. FFN + LN2 + pred
    gemm_bf16<<<gN512, 256, 0, stream>>>(Sb_b, Sb_b, BIG, Wb + oW1, b1, H1_b, nullptr, 512, 1, 0);
    gemm_bf16<<<gN512, 256, 0, stream>>>(H1_b, H1_b, BIG, Wb + oW2, b2, nullptr, Fpre_f, 512, 0, 0);
    ln_kernel<<<8192, 256, 0, stream>>>(Fpre_f, Sbuf_f, nullptr, ln2_g, ln2_b, Fbuf_f, nullptr);
    pred_kernel<<<2048, 256, 0, stream>>>(Fbuf_f, pred_w, pred_b, out);
}

// Round 6
// 526.716 us; speedup vs baseline: 16.7368x; 1.0153x over previous
//
#include <hip/hip_runtime.h>
#include <hip/hip_bf16.h>

#define D_MODEL 512
#define NHEAD 8
#define NSEQ 512
#define BATCH 16
#define LWIN 64
#define S2C 0.18033688f   // 0.125 * log2(e)
#define L2E 1.44269504f

typedef short s16x8 __attribute__((ext_vector_type(8)));
typedef float f32x4 __attribute__((ext_vector_type(4)));

__device__ inline unsigned short f2bf(float f) {
    unsigned int u = __float_as_uint(f);
    u = (u + 0x7fffu + ((u >> 16) & 1u)) >> 16;   // RNE
    return (unsigned short)u;
}
__device__ inline int sw4(int r) { return (r + (r >> 2)) & 3; }

#define GLD16(g, l) __builtin_amdgcn_global_load_lds( \
    (const __attribute__((address_space(1))) void*)(g), \
    (__attribute__((address_space(3))) void*)(l), 16, 0, 0)

// ---------------------------------------------------------------------------
// weight convert: pack 10 fp32 weight matrices into one bf16 region
// ---------------------------------------------------------------------------
struct WP { const float* p[10]; };
__global__ __launch_bounds__(256) void wconv_kernel(WP wp, unsigned short* __restrict__ Wb)
{
    const long e = ((long)blockIdx.x * 256 + threadIdx.x) * 4;
    const float* src; long loc;
    if (e < 3145728) { int rg = (int)(e / 786432); src = wp.p[rg]; loc = e - (long)rg * 786432; }
    else { long j = e - 3145728; int rg = (int)(j >> 18); src = wp.p[4 + rg]; loc = j - ((long)rg << 18); }
    float4 v = *(const float4*)(src + loc);
    ushort4 o; o.x = f2bf(v.x); o.y = f2bf(v.y); o.z = f2bf(v.z); o.w = f2bf(v.w);
    *(ushort4*)(Wb + e) = o;
}

// ---------------------------------------------------------------------------
// embed
// ---------------------------------------------------------------------------
__global__ __launch_bounds__(128) void embed_kernel(
    const int* __restrict__ q, const int* __restrict__ r, const int* __restrict__ qry,
    const float* __restrict__ M_emb, const float* __restrict__ E_emb,
    const float* __restrict__ P, float* __restrict__ Mf, float* __restrict__ Ef,
    unsigned short* __restrict__ Mb, unsigned short* __restrict__ Eb)
{
    const int t = blockIdx.x;              // b*N + n
    const int n = t & (NSEQ - 1);
    const int x = q[t] + 10000 * r[t];
    const int e = qry[t];
    const int i = threadIdx.x;
    float4 a = ((const float4*)(M_emb + (long)x * D_MODEL))[i];
    float4 p4 = ((const float4*)(P + (long)n * D_MODEL))[i];
    float4 ev = ((const float4*)(E_emb + (long)e * D_MODEL))[i];
    float4 mv = make_float4(a.x + p4.x, a.y + p4.y, a.z + p4.z, a.w + p4.w);
    ((float4*)(Mf + (long)t * D_MODEL))[i] = mv;
    ((float4*)(Ef + (long)t * D_MODEL))[i] = ev;
    ushort4 mb; mb.x = f2bf(mv.x); mb.y = f2bf(mv.y); mb.z = f2bf(mv.z); mb.w = f2bf(mv.w);
    ushort4 eb; eb.x = f2bf(ev.x); eb.y = f2bf(ev.y); eb.z = f2bf(ev.z); eb.w = f2bf(ev.w);
    *(ushort4*)(Mb + (long)t * D_MODEL + i * 4) = mb;
    *(ushort4*)(Eb + (long)t * D_MODEL + i * 4) = eb;
}

// zero-fill bf16 buffer (uint4 granularity)
__global__ __launch_bounds__(256) void zfill_kernel(unsigned short* __restrict__ p)
{
    const long i = ((long)blockIdx.x * 256 + threadIdx.x) * 8;
    *(uint4*)(p + i) = make_uint4(0u, 0u, 0u, 0u);
}

// ---------------------------------------------------------------------------
// bf16 MFMA GEMM with async global_load_lds staging (m97 pattern) and
// coalesced LDS-restaged epilogue with fusion modes.
// C[M x N] = Asel[M x 512] @ W[N x 512]^T + bias
//  - Asel = (n0 >= nsplit) ? A2 : A
//  - arem: A-row remap row -> (row>>6)*512 + 448 + (row&63)
//  - crem: Cb-row remap (same formula) for S_local scatter
//  - r1/r2/tl: fused residual adds (fp32); tl is sparse (rows n>=448)
// 128x128 tile, BK=32, 256 thr = 4 waves, 4x4 mfma 16x16x32.
// ---------------------------------------------------------------------------
__global__ __launch_bounds__(256) void gemm_bf16(
    const unsigned short* __restrict__ A, const unsigned short* __restrict__ A2, int nsplit,
    const unsigned short* __restrict__ W, const float* __restrict__ bias,
    unsigned short* __restrict__ Cb, int ldcb, int crem,
    float* __restrict__ Cf, int ldcf,
    const float* __restrict__ r1, const float* __restrict__ r2, const float* __restrict__ tl,
    int relu, int arem)
{
    __shared__ __align__(16) unsigned short Sh[8704];   // K-loop: As 4096 | Ws 4096 ; epilogue: 32x132 fp32
    unsigned short* As = Sh;
    unsigned short* Ws = Sh + 4096;
    float* Shf = (float*)Sh;

    const int tid = threadIdx.x, lane = tid & 63, wid = tid >> 6;
    const int m0 = blockIdx.y * 128, n0 = blockIdx.x * 128;
    const int mbase = (wid >> 1) * 64, nbase = (wid & 1) * 64;
    const int fr = lane & 15;          // C col / frag row
    const int lq = lane >> 4;          // frag k-group
    const unsigned short* Asel = (n0 >= nsplit) ? A2 : A;

    // ---- async staging setup: lane -> (row, chunk) with XOR swizzle on global side ----
    const int rlane = lane >> 2, clane = lane & 3;
    const int lrA0 = wid * 16 + rlane, lrA1 = 64 + wid * 16 + rlane;
    int rgA0 = m0 + lrA0, rgA1 = m0 + lrA1;
    if (arem) {
        rgA0 = ((rgA0 >> 6) << 9) + (NSEQ - LWIN) + (rgA0 & 63);
        rgA1 = ((rgA1 >> 6) << 9) + (NSEQ - LWIN) + (rgA1 & 63);
    }
    const unsigned short* pA0 = Asel + (long)rgA0 * 512 + ((clane ^ sw4(lrA0)) << 3);
    const unsigned short* pA1 = Asel + (long)rgA1 * 512 + ((clane ^ sw4(lrA1)) << 3);
    const unsigned short* pW0 = W + (long)(n0 + lrA0) * 512 + ((clane ^ sw4(lrA0)) << 3);
    const unsigned short* pW1 = W + (long)(n0 + lrA1) * 512 + ((clane ^ sw4(lrA1)) << 3);
    unsigned short* lA0 = As + (wid * 16) * 32;        // wave-uniform LDS bases
    unsigned short* lA1 = As + (64 + wid * 16) * 32;
    unsigned short* lW0 = Ws + (wid * 16) * 32;
    unsigned short* lW1 = Ws + (64 + wid * 16) * 32;

    f32x4 acc[4][4];
    #pragma unroll
    for (int i = 0; i < 4; ++i)
        #pragma unroll
        for (int j = 0; j < 4; ++j) acc[i][j] = (f32x4){0.f, 0.f, 0.f, 0.f};

    for (int k0 = 0; k0 < 512; k0 += 32) {
        __syncthreads();                       // prior frag reads done
        GLD16(pA0 + k0, lA0);
        GLD16(pA1 + k0, lA1);
        GLD16(pW0 + k0, lW0);
        GLD16(pW1 + k0, lW1);
        __syncthreads();                       // drains vmcnt -> staged data visible

        s16x8 af[4], wf[4];
        #pragma unroll
        for (int t = 0; t < 4; ++t) {
            const int ra = mbase + t * 16 + fr;
            const int rw = nbase + t * 16 + fr;
            af[t] = *(const s16x8*)&As[ra * 32 + ((lq ^ sw4(ra)) << 3)];
            wf[t] = *(const s16x8*)&Ws[rw * 32 + ((lq ^ sw4(rw)) << 3)];
        }
        #pragma unroll
        for (int i = 0; i < 4; ++i)
            #pragma unroll
            for (int j = 0; j < 4; ++j)
                acc[i][j] = __builtin_amdgcn_mfma_f32_16x16x32_bf16(af[i], wf[j], acc[i][j], 0, 0, 0);
    }

    // ---- epilogue: 4 quarter-passes (32 rows x 128 cols fp32 through LDS) ----
    const int q4 = (lane >> 4) * 4;
    for (int qtr = 0; qtr < 4; ++qtr) {
        __syncthreads();
        if ((wid >> 1) == (qtr >> 1)) {
            const int ibase = (qtr & 1) * 2;
            #pragma unroll
            for (int j = 0; j < 4; ++j) {
                const int lcol = nbase + j * 16 + fr;
                const float bv = bias[n0 + lcol];
                #pragma unroll
                for (int i2 = 0; i2 < 2; ++i2) {
                    const int i = ibase + i2;
                    #pragma unroll
                    for (int rg = 0; rg < 4; ++rg) {
                        float v = acc[i][j][rg] + bv;
                        if (relu) v = fmaxf(v, 0.f);
                        Shf[((i * 16 + q4 + rg) & 31) * 132 + lcol] = v;
                    }
                }
            }
        }
        __syncthreads();
        #pragma unroll
        for (int it = 0; it < 4; ++it) {
            const int flat = it * 256 + tid;
            const int rowq = flat >> 5, k4 = flat & 31;
            const int grow = m0 + qtr * 32 + rowq;
            const int gcol = n0 + k4 * 4;
            float4 f = *(const float4*)&Shf[rowq * 132 + k4 * 4];
            if (r1) {
                float4 a = *(const float4*)(r1 + (long)grow * 512 + gcol);
                float4 b = *(const float4*)(r2 + (long)grow * 512 + gcol);
                f.x += a.x + b.x; f.y += a.y + b.y; f.z += a.z + b.z; f.w += a.w + b.w;
                const int n = grow & 511;
                if (n >= NSEQ - LWIN) {
                    float4 c = *(const float4*)(tl + ((long)(grow >> 9) * 64 + (n - (NSEQ - LWIN))) * 512 + gcol);
                    f.x += c.x; f.y += c.y; f.z += c.z; f.w += c.w;
                }
            }
            if (Cf) *(float4*)(Cf + (long)grow * ldcf + gcol) = f;
            if (Cb) {
                const int crow = crem ? (((grow >> 6) << 9) + (NSEQ - LWIN) + (grow & 63)) : grow;
                ushort4 u; u.x = f2bf(f.x); u.y = f2bf(f.y); u.z = f2bf(f.z); u.w = f2bf(f.w);
                *(ushort4*)(Cb + (long)crow * ldcb + gcol) = u;
            }
        }
    }
}

// ---------------------------------------------------------------------------
// Transposed MFMA flash attention, paired q-tiles. (unchanged from R5)
// ---------------------------------------------------------------------------
__global__ __launch_bounds__(256) void flash_mfma(
    const unsigned short* __restrict__ Q, const unsigned short* __restrict__ K,
    const unsigned short* __restrict__ V, unsigned short* __restrict__ O,
    float* __restrict__ stats, int Nq, int Nkv, int ldq, int ldkv, int causal)
{
    __shared__ __align__(16) unsigned short Ks[64 * 72];   // [key][dim]
    __shared__ __align__(16) unsigned short Pl[64 * 72];   // [q][key] bf16
    __shared__ __align__(16) unsigned int   Vt[64 * 36];   // [dim][keypair] swizzled

    const int tid = threadIdx.x, lane = tid & 63, w = tid >> 6;
    const int lm = lane & 15, lq = lane >> 4;
    const int h = blockIdx.y, b = blockIdx.z;
    const int nqt = Nq >> 6;
    const int qa = blockIdx.x, qb = nqt - 1 - qa;
    const bool single = (qa == qb);

    s16x8 aqA0, aqA1, aqB0, aqB1;
    {
        const unsigned short* qp = Q + ((long)b * Nq + qb * 64 + w * 16 + lm) * ldq + h * 64 + lq * 8;
        aqB0 = *(const s16x8*)qp; aqB1 = *(const s16x8*)(qp + 32);
    }
    if (!single) {
        const unsigned short* qp = Q + ((long)b * Nq + qa * 64 + w * 16 + lm) * ldq + h * 64 + lq * 8;
        aqA0 = *(const s16x8*)qp; aqA1 = *(const s16x8*)(qp + 32);
    }

    float mA = -INFINITY, lA = 0.f, mB = -INFINITY, lB = 0.f;
    f32x4 oA[4], oB[4];
    #pragma unroll
    for (int t = 0; t < 4; ++t) { oA[t] = (f32x4){0.f,0.f,0.f,0.f}; oB[t] = (f32x4){0.f,0.f,0.f,0.f}; }

    const int nkt = causal ? (qb + 1) : (Nkv >> 6);
    const int skey = tid >> 3, sd = (tid & 7) * 8;

    s16x8 kr0, kr1; uint4 vr0, vr1;
    {
        const long kb = ((long)b * Nkv) * ldkv + h * 64;
        kr0 = *(const s16x8*)(K + kb + (long)skey * ldkv + sd);
        kr1 = *(const s16x8*)(K + kb + (long)(skey + 32) * ldkv + sd);
        const unsigned short* vp = V + ((long)b * Nkv + 2 * skey) * ldkv + h * 64 + sd;
        vr0 = *(const uint4*)vp; vr1 = *(const uint4*)(vp + ldkv);
    }

    auto process = [&](s16x8 a0, s16x8 a1, float& m, float& l, f32x4* oacc, bool diag) {
        f32x4 sc[4];
        #pragma unroll
        for (int t = 0; t < 4; ++t) sc[t] = (f32x4){0.f,0.f,0.f,0.f};
        #pragma unroll
        for (int t = 0; t < 4; ++t) {
            s16x8 k0 = *(const s16x8*)&Ks[(t * 16 + lm) * 72 + lq * 8];
            s16x8 k1 = *(const s16x8*)&Ks[(t * 16 + lm) * 72 + lq * 8 + 32];
            sc[t] = __builtin_amdgcn_mfma_f32_16x16x32_bf16(k0, a0, sc[t], 0, 0, 0);
            sc[t] = __builtin_amdgcn_mfma_f32_16x16x32_bf16(k1, a1, sc[t], 0, 0, 0);
        }
        if (diag) {
            #pragma unroll
            for (int t = 0; t < 4; ++t)
                #pragma unroll
                for (int r = 0; r < 4; ++r)
                    if (t * 16 + lq * 4 + r > w * 16 + lm) sc[t][r] = -INFINITY;
        }
        float mt = sc[0][0];
        #pragma unroll
        for (int t = 0; t < 4; ++t)
            #pragma unroll
            for (int r = 0; r < 4; ++r) mt = fmaxf(mt, sc[t][r]);
        mt = fmaxf(mt, __shfl_xor(mt, 16));
        mt = fmaxf(mt, __shfl_xor(mt, 32));
        const float mn = fmaxf(m, mt);
        const float al = exp2f((m - mn) * S2C);
        float rs = 0.f;
        #pragma unroll
        for (int t = 0; t < 4; ++t)
            #pragma unroll
            for (int r = 0; r < 4; ++r) {
                float p = exp2f((sc[t][r] - mn) * S2C);
                sc[t][r] = p; rs += p;
            }
        rs += __shfl_xor(rs, 16);
        rs += __shfl_xor(rs, 32);
        m = mn; l = l * al + rs;
        #pragma unroll
        for (int t = 0; t < 4; ++t) oacc[t] *= al;
        #pragma unroll
        for (int t = 0; t < 4; ++t) {
            ushort4 u;
            u.x = f2bf(sc[t][0]); u.y = f2bf(sc[t][1]);
            u.z = f2bf(sc[t][2]); u.w = f2bf(sc[t][3]);
            *(ushort4*)&Pl[(w * 16 + lm) * 72 + t * 16 + lq * 4] = u;
        }
        #pragma unroll
        for (int ks = 0; ks < 2; ++ks) {
            s16x8 bp = *(const s16x8*)&Pl[(w * 16 + lm) * 72 + ks * 32 + lq * 8];
            #pragma unroll
            for (int t = 0; t < 4; ++t) {
                const int row = t * 16 + lm;
                const int pg = ((lq >> 1) + 2 * ks) ^ ((row >> 3) & 3);
                s16x8 av = *(const s16x8*)((const unsigned short*)Vt + row * 72 + pg * 16 + (lq & 1) * 8);
                oacc[t] = __builtin_amdgcn_mfma_f32_16x16x32_bf16(av, bp, oacc[t], 0, 0, 0);
            }
        }
    };

    for (int kt = 0; kt < nkt; ++kt) {
        __syncthreads();
        *(s16x8*)&Ks[skey * 72 + sd] = kr0;
        *(s16x8*)&Ks[(skey + 32) * 72 + sd] = kr1;
        {
            unsigned pw[8];
            pw[0] = (vr0.x & 0xffffu) | (vr1.x << 16);
            pw[1] = (vr0.x >> 16)     | (vr1.x & 0xffff0000u);
            pw[2] = (vr0.y & 0xffffu) | (vr1.y << 16);
            pw[3] = (vr0.y >> 16)     | (vr1.y & 0xffff0000u);
            pw[4] = (vr0.z & 0xffffu) | (vr1.z << 16);
            pw[5] = (vr0.z >> 16)     | (vr1.z & 0xffff0000u);
            pw[6] = (vr0.w & 0xffffu) | (vr1.w << 16);
            pw[7] = (vr0.w >> 16)     | (vr1.w & 0xffff0000u);
            #pragma unroll
            for (int j = 0; j < 8; ++j) {
                const int row = sd + j;
                const int col = (((skey >> 3) ^ ((row >> 3) & 3)) << 3) | (skey & 7);
                Vt[row * 36 + col] = pw[j];
            }
        }
        __syncthreads();
        if (kt + 1 < nkt) {
            const long kb = ((long)b * Nkv + (kt + 1) * 64) * ldkv + h * 64;
            kr0 = *(const s16x8*)(K + kb + (long)skey * ldkv + sd);
            kr1 = *(const s16x8*)(K + kb + (long)(skey + 32) * ldkv + sd);
            const unsigned short* vp = V + ((long)b * Nkv + (kt + 1) * 64 + 2 * skey) * ldkv + h * 64 + sd;
            vr0 = *(const uint4*)vp; vr1 = *(const uint4*)(vp + ldkv);
        }
        process(aqB0, aqB1, mB, lB, oB, causal && (kt == qb));
        if (!single && (!causal || kt <= qa))
            process(aqA0, aqA1, mA, lA, oA, causal && (kt == qa));
    }

    {
        const float inv = 1.0f / lB;
        const long orow = ((long)b * Nq + qb * 64 + w * 16 + lm) * D_MODEL + h * 64;
        #pragma unroll
        for (int t = 0; t < 4; ++t) {
            ushort4 u;
            u.x = f2bf(oB[t][0] * inv); u.y = f2bf(oB[t][1] * inv);
            u.z = f2bf(oB[t][2] * inv); u.w = f2bf(oB[t][3] * inv);
            *(ushort4*)(O + orow + t * 16 + lq * 4) = u;
        }
    }
    if (!single) {
        const float inv = 1.0f / lA;
        const long orow = ((long)b * Nq + qa * 64 + w * 16 + lm) * D_MODEL + h * 64;
        #pragma unroll
        for (int t = 0; t < 4; ++t) {
            ushort4 u;
            u.x = f2bf(oA[t][0] * inv); u.y = f2bf(oA[t][1] * inv);
            u.z = f2bf(oA[t][2] * inv); u.w = f2bf(oA[t][3] * inv);
            *(ushort4*)(O + orow + t * 16 + lq * 4) = u;
        }
    }
    if (stats && lq == 0) {
        long idx = (((long)b * NHEAD + h) * Nq + qb * 64 + w * 16 + lm) * 2;
        stats[idx] = mB * 0.125f; stats[idx + 1] = lB;
        if (!single) {
            idx = (((long)b * NHEAD + h) * Nq + qa * 64 + w * 16 + lm) * 2;
            stats[idx] = mA * 0.125f; stats[idx + 1] = lA;
        }
    }
}

// ---------------------------------------------------------------------------
// attn_w (transposed MFMA): head-mean base probs via saved (m,l). grid (8,8,B).
// ---------------------------------------------------------------------------
__global__ __launch_bounds__(256) void attn_w_kernel(
    const unsigned short* __restrict__ Q, const unsigned short* __restrict__ K,
    const float* __restrict__ stats, float* __restrict__ AW, int ldq, int ldk)
{
    const int kt = blockIdx.x, qt = blockIdx.y, b = blockIdx.z;
    const int tid = threadIdx.x;
    if (kt > qt) {
        const int tx = tid & 15, ty = tid >> 4;
        #pragma unroll
        for (int i = 0; i < 4; ++i)
            *(float4*)(AW + ((long)b * NSEQ + qt * 64 + ty * 4 + i) * NSEQ + kt * 64 + tx * 4)
                = make_float4(0.f, 0.f, 0.f, 0.f);
        return;
    }
    __shared__ __align__(16) unsigned short Ks[64 * 72];
    const int lane = tid & 63, w = tid >> 6;
    const int lm = lane & 15, lq = lane >> 4;
    const int skey = tid >> 3, sd = (tid & 7) * 8;
    const long qrow = (long)b * NSEQ + qt * 64 + w * 16 + lm;

    f32x4 aw[4];
    #pragma unroll
    for (int t = 0; t < 4; ++t) aw[t] = (f32x4){0.f,0.f,0.f,0.f};

    for (int h = 0; h < NHEAD; ++h) {
        __syncthreads();
        {
            const long kb = ((long)b * NSEQ + kt * 64) * ldk + h * 64;
            *(s16x8*)&Ks[skey * 72 + sd] = *(const s16x8*)(K + kb + (long)skey * ldk + sd);
            *(s16x8*)&Ks[(skey + 32) * 72 + sd] = *(const s16x8*)(K + kb + (long)(skey + 32) * ldk + sd);
        }
        __syncthreads();
        s16x8 a0, a1;
        {
            const unsigned short* qp = Q + qrow * ldq + h * 64 + lq * 8;
            a0 = *(const s16x8*)qp; a1 = *(const s16x8*)(qp + 32);
        }
        f32x4 sc[4];
        #pragma unroll
        for (int t = 0; t < 4; ++t) sc[t] = (f32x4){0.f,0.f,0.f,0.f};
        #pragma unroll
        for (int t = 0; t < 4; ++t) {
            s16x8 k0 = *(const s16x8*)&Ks[(t * 16 + lm) * 72 + lq * 8];
            s16x8 k1 = *(const s16x8*)&Ks[(t * 16 + lm) * 72 + lq * 8 + 32];
            sc[t] = __builtin_amdgcn_mfma_f32_16x16x32_bf16(k0, a0, sc[t], 0, 0, 0);
            sc[t] = __builtin_amdgcn_mfma_f32_16x16x32_bf16(k1, a1, sc[t], 0, 0, 0);
        }
        float2 ml = *(const float2*)(stats + (((long)b * NHEAD + h) * NSEQ + qt * 64 + w * 16 + lm) * 2);
        const float mb2 = ml.x * L2E;
        const float sca = 0.125f / ml.y;
        #pragma unroll
        for (int t = 0; t < 4; ++t)
            #pragma unroll
            for (int r = 0; r < 4; ++r) {
                const bool masked = (kt == qt) && (t * 16 + lq * 4 + r > w * 16 + lm);
                if (!masked) aw[t][r] += exp2f(sc[t][r] * S2C - mb2) * sca;
            }
    }
    #pragma unroll
    for (int t = 0; t < 4; ++t)
        *(float4*)(AW + qrow * NSEQ + kt * 64 + t * 16 + lq * 4) = float4{aw[t][0], aw[t][1], aw[t][2], aw[t][3]};
}

// ---------------------------------------------------------------------------
// LayerNorm: out = LN(X + R1 + R2)*g + b ; optional bf16 copy; optional
// fused prediction head (pw/pb/outp): skips LN output entirely.
// ---------------------------------------------------------------------------
__global__ __launch_bounds__(256) void ln_kernel(
    const float* __restrict__ X, const float* __restrict__ R1,
    const float* __restrict__ R2, const float* __restrict__ g,
    const float* __restrict__ bb, float* __restrict__ outf,
    unsigned short* __restrict__ outb,
    const float* __restrict__ pw, const float* __restrict__ pb,
    float* __restrict__ outp)
{
    const long row = blockIdx.x;
    const int tid = threadIdx.x;
    __shared__ float red[256];
    const long base = row * D_MODEL;
    float v0 = X[base + tid], v1 = X[base + tid + 256];
    if (R1) { v0 += R1[base + tid]; v1 += R1[base + tid + 256]; }
    if (R2) { v0 += R2[base + tid]; v1 += R2[base + tid + 256]; }
    red[tid] = v0 + v1; __syncthreads();
    for (int s = 128; s > 0; s >>= 1) {
        if (tid < s) red[tid] += red[tid + s];
        __syncthreads();
    }
    const float mean = red[0] * (1.f / 512.f);
    __syncthreads();
    const float d0 = v0 - mean, d1 = v1 - mean;
    red[tid] = d0 * d0 + d1 * d1; __syncthreads();
    for (int s = 128; s > 0; s >>= 1) {
        if (tid < s) red[tid] += red[tid + s];
        __syncthreads();
    }
    const float rstd = rsqrtf(red[0] * (1.f / 512.f) + 1e-5f);
    const float y0 = d0 * rstd * g[tid] + bb[tid];
    const float y1 = d1 * rstd * g[tid + 256] + bb[tid + 256];
    if (pw) {
        float s = y0 * pw[tid] + y1 * pw[tid + 256];
        __syncthreads();
        red[tid] = s; __syncthreads();
        for (int st = 128; st > 0; st >>= 1) {
            if (tid < st) red[tid] += red[tid + st];
            __syncthreads();
        }
        if (tid == 0) outp[row] = 1.f / (1.f + __expf(-(red[0] + pb[0])));
        return;
    }
    if (outf) { outf[base + tid] = y0; outf[base + tid + 256] = y1; }
    if (outb) { outb[base + tid] = f2bf(y0); outb[base + tid + 256] = f2bf(y1); }
}

// ---------------------------------------------------------------------------
extern "C" void kernel_launch(void* const* d_in, const int* in_sizes, int n_in,
                              void* d_out, int out_size, void* d_ws, size_t ws_size,
                              hipStream_t stream)
{
    const int*   q          = (const int*)d_in[0];
    const int*   r          = (const int*)d_in[1];
    const int*   qry        = (const int*)d_in[2];
    const float* M_emb      = (const float*)d_in[3];
    const float* E_emb      = (const float*)d_in[4];
    const float* P          = (const float*)d_in[5];
    const float* base_in_w  = (const float*)d_in[6];
    const float* base_in_b  = (const float*)d_in[7];
    const float* base_out_w = (const float*)d_in[8];
    const float* base_out_b = (const float*)d_in[9];
    const float* local_in_w = (const float*)d_in[10];
    const float* local_in_b = (const float*)d_in[11];
    const float* local_out_w= (const float*)d_in[12];
    const float* local_out_b= (const float*)d_in[13];
    const float* glob_in_w  = (const float*)d_in[14];
    const float* glob_in_b  = (const float*)d_in[15];
    const float* glob_out_w = (const float*)d_in[16];
    const float* glob_out_b = (const float*)d_in[17];
    const float* cross_in_w = (const float*)d_in[18];
    const float* cross_in_b = (const float*)d_in[19];
    const float* cross_out_w= (const float*)d_in[20];
    const float* cross_out_b= (const float*)d_in[21];
    const float* ln1_g      = (const float*)d_in[22];
    const float* ln1_b      = (const float*)d_in[23];
    const float* w1         = (const float*)d_in[24];
    const float* b1         = (const float*)d_in[25];
    const float* w2         = (const float*)d_in[26];
    const float* b2         = (const float*)d_in[27];
    const float* ln2_g      = (const float*)d_in[28];
    const float* ln2_b      = (const float*)d_in[29];
    const float* pred_w     = (const float*)d_in[30];
    const float* pred_b     = (const float*)d_in[31];
    float* out = (float*)d_out;

    // ---- workspace carve-up ----
    char* p = (char*)d_ws;
    unsigned short* Wb = (unsigned short*)p; p += 4718592L * 2;        // 9.44 MB
    unsigned short* B[11];
    for (int i = 0; i < 11; ++i) { B[i] = (unsigned short*)p; p += 8388608L; }  // 8 MB each
    unsigned short* Obl  = (unsigned short*)p; p += 1048576L;
    float* R[4];
    for (int i = 0; i < 4; ++i) { R[i] = (float*)p; p += 16777216L; }
    float* Tloc  = (float*)p; p += 2097152L;
    float* stats = (float*)p; p += 524288L;

    // bf16 buffers
    unsigned short* Mb = B[0];
    unsigned short* Eb = B[1];      unsigned short* Oc_b = B[1];
    unsigned short* QKVb = B[2];    // base QKV (spans B[2..4]); later cross QKV; later Sb_b
    unsigned short* Sb_b = B[2];
    unsigned short* Ob  = B[5];     // base attn out; later glob attn out
    unsigned short* Sbase_b  = B[6];
    unsigned short* Slocal_b = B[7];
    unsigned short* QKV3 = B[8];    // local QKV, then glob QKV (spans B[8..10]); later H1
    unsigned short* H1_b = B[8];
    // fp32 buffers
    float* Mf = R[0];
    float* Ef = R[1];       float* Sbuf_f   = R[1];
    float* Tb_f = R[2];     float* Sglobal_f= R[2];
    float* Sbase_f = R[3];  float* Fpre_f   = R[3];

    // weight sub-offsets in Wb (elements)
    const long oBin = 0, oLin = 786432, oGin = 1572864, oCin = 2359296;
    const long oBout = 3145728, oLout = 3407872, oGout = 3670016, oCout = 3932160;
    const long oW1 = 4194304, oW2 = 4456448;
    const int BIG = 1 << 30;
    const unsigned short* NUS = nullptr;
    const float* NF = nullptr;

    dim3 gN512(4, 64), gN1536(12, 64);
    dim3 gL1536(12, 8), gL512(4, 8);
    dim3 fa_full(4, NHEAD, BATCH), fa_loc(1, NHEAD, BATCH);

    // 0. weights -> bf16 ; zero S_local prefix region (full buffer)
    WP wp; wp.p[0] = base_in_w; wp.p[1] = local_in_w; wp.p[2] = glob_in_w; wp.p[3] = cross_in_w;
    wp.p[4] = base_out_w; wp.p[5] = local_out_w; wp.p[6] = glob_out_w; wp.p[7] = cross_out_w;
    wp.p[8] = w1; wp.p[9] = w2;
    wconv_kernel<<<4608, 256, 0, stream>>>(wp, Wb);
    zfill_kernel<<<2048, 256, 0, stream>>>(Slocal_b);   // 16*512*512 bf16

    // 1. embeddings
    embed_kernel<<<8192, 128, 0, stream>>>(q, r, qry, M_emb, E_emb, P, Mf, Ef, Mb, Eb);

    // 2. base MHA: fused QKV (Q from E, K/V from M), flash, attn_w, out-proj, ln1
    gemm_bf16<<<gN1536, 256, 0, stream>>>(Eb, Mb, 512, Wb + oBin, base_in_b,
        QKVb, 1536, 0, nullptr, 0, NF, NF, NF, 0, 0);
    flash_mfma<<<fa_full, 256, 0, stream>>>(QKVb, QKVb + 512, QKVb + 1024, Ob, stats, 512, 512, 1536, 1536, 1);
    attn_w_kernel<<<dim3(8, 8, BATCH), 256, 0, stream>>>(QKVb, QKVb + 512, stats, out + 8192, 1536, 1536);
    gemm_bf16<<<gN512, 256, 0, stream>>>(Ob, NUS, BIG, Wb + oBout, base_out_b,
        nullptr, 0, 0, Tb_f, 512, NF, NF, NF, 0, 0);
    ln_kernel<<<8192, 256, 0, stream>>>(Tb_f, Mf, Ef, ln1_g, ln1_b, Sbase_f, Sbase_b, NF, NF, nullptr);

    // 3. local MHA (last 64 tokens; A-row remap in, C-row remap out)
    gemm_bf16<<<gL1536, 256, 0, stream>>>(Sbase_b, NUS, BIG, Wb + oLin, local_in_b,
        QKV3, 1536, 0, nullptr, 0, NF, NF, NF, 0, 1);
    flash_mfma<<<fa_loc, 256, 0, stream>>>(QKV3, QKV3 + 512, QKV3 + 1024, Obl, nullptr, 64, 64, 1536, 1536, 1);
    gemm_bf16<<<gL512, 256, 0, stream>>>(Obl, NUS, BIG, Wb + oLout, local_out_b,
        Slocal_b, 512, 1, Tloc, 512, NF, NF, NF, 0, 0);

    // 4. global MHA (S_base self-attn, causal)
    gemm_bf16<<<gN1536, 256, 0, stream>>>(Sbase_b, NUS, BIG, Wb + oGin, glob_in_b,
        QKV3, 1536, 0, nullptr, 0, NF, NF, NF, 0, 0);
    flash_mfma<<<fa_full, 256, 0, stream>>>(QKV3, QKV3 + 512, QKV3 + 1024, Ob, nullptr, 512, 512, 1536, 1536, 1);
    gemm_bf16<<<gN512, 256, 0, stream>>>(Ob, NUS, BIG, Wb + oGout, glob_out_b,
        nullptr, 0, 0, Sglobal_f, 512, NF, NF, NF, 0, 0);

    // 5. cross MHA (Q from S_base, K/V from S_local) + fused S-sum epilogue
    gemm_bf16<<<gN1536, 256, 0, stream>>>(Sbase_b, Slocal_b, 512, Wb + oCin, cross_in_b,
        QKVb, 1536, 0, nullptr, 0, NF, NF, NF, 0, 0);
    flash_mfma<<<fa_full, 256, 0, stream>>>(QKVb, QKVb + 512, QKVb + 1024, Oc_b, nullptr, 512, 512, 1536, 1536, 0);
    gemm_bf16<<<gN512, 256, 0, stream>>>(Oc_b, NUS, BIG, Wb + oCout, cross_out_b,
        Sb_b, 512, 0, Sbuf_f, 512, Sbase_f, Sglobal_f, Tloc, 0, 0);

    // 6. FFN + fused LN2+pred
    gemm_bf16<<<gN512, 256, 0, stream>>>(Sb_b, NUS, BIG, Wb + oW1, b1,
        H1_b, 512, 0, nullptr, 0, NF, NF, NF, 1, 0);
    gemm_bf16<<<gN512, 256, 0, stream>>>(H1_b, NUS, BIG, Wb + oW2, b2,
        nullptr, 0, 0, Fpre_f, 512, NF, NF, NF, 0, 0);
    ln_kernel<<<8192, 256, 0, stream>>>(Fpre_f, Sbuf_f, nullptr, ln2_g, ln2_b,
        nullptr, nullptr, pred_w, pred_b, out);
}